// Round 9
// baseline (192.335 us; speedup 1.0000x reference)
//
#include <hip/hip_runtime.h>
#include <math.h>

#define EPS_ 1e-10f
#define MARGIN 2e-3f

__device__ __forceinline__ bool betterd(double v, int i, double w, int j) {
    return (v > w) || (v == w && i < j);
}

// ---------------------------------------------------------------------------
// GEMM: block = 256 thr (4 waves) = 64 rows x 64 experts, one K-slice.
// lane = row; wave w owns experts [16w,16w+16) via readfirstlane -> W loads
// scalarize to s_load_dwordx16 (SGPR operands feed FMAs directly).
// Fix vs R8: xv[16] is PINNED into VGPRs via asm keep-alive so the compiler
// cannot fold the ds_reads back into the FMA loop -> the FMA region's
// lgkmcnt waits cover only the s_load chain (4-deep pipelined).
// LDS pad 66 (write conflicts 4-way -> 2-way=free, reads 2-way=free).
// Grid = ksplit * (N/64) = 2048 blocks -> 8 blocks/CU, 8 waves/SIMD.
// zpart[ks][e][row] (lane-coalesced stores).
// ---------------------------------------------------------------------------
#define KW 16
__global__ __launch_bounds__(256, 8)
void gemm_rows(const float* __restrict__ x, const float* __restrict__ W,
               int dim, int N, int ks_count, int rgs,
               float* __restrict__ zpart)
{
    __shared__ float xT[2][KW][66];   // [buf][k][row]; pad 66 -> <=2-way banks

    const int tid  = threadIdx.x;
    const int lane = tid & 63;                                   // row
    const int e0   = __builtin_amdgcn_readfirstlane((tid >> 6) << 4);
    const int ks = blockIdx.x / rgs;
    const int rg = blockIdx.x % rgs;
    const int r0 = rg * 64;
    const int kslice = dim / ks_count;
    const int k0 = ks * kslice;
    const int nwin = kslice / KW;

    // staging: 256 threads x one float4 = 64 rows x 16 k
    const int srow = tid >> 2;           // 0..63
    const int sk4  = (tid & 3) * 4;      // 0,4,8,12

    float acc[16];
#pragma unroll
    for (int e = 0; e < 16; ++e) acc[e] = 0.0f;

    const float* xsrc  = x + (size_t)(r0 + srow) * dim + k0 + sk4;
    const float* wbase = W + e0;         // SGPR-uniform base

    // prologue: stage window 0, prefetch window 1
    float4 va = *(const float4*)xsrc;
    xT[0][sk4 + 0][srow] = va.x; xT[0][sk4 + 1][srow] = va.y;
    xT[0][sk4 + 2][srow] = va.z; xT[0][sk4 + 3][srow] = va.w;
    float4 vn;
    if (nwin > 1) vn = *(const float4*)(xsrc + KW);
    __syncthreads();

    int cur = 0;
    for (int w = 0; w < nwin; ++w) {
        // pre-read x window into registers, then PIN them there
        float xv[KW];
#pragma unroll
        for (int k = 0; k < KW; ++k) xv[k] = xT[cur][k][lane];
        asm volatile("" :
            "+v"(xv[0]),  "+v"(xv[1]),  "+v"(xv[2]),  "+v"(xv[3]),
            "+v"(xv[4]),  "+v"(xv[5]),  "+v"(xv[6]),  "+v"(xv[7]),
            "+v"(xv[8]),  "+v"(xv[9]),  "+v"(xv[10]), "+v"(xv[11]),
            "+v"(xv[12]), "+v"(xv[13]), "+v"(xv[14]), "+v"(xv[15]));

        // stage next window into the other buffer
        if (w + 1 < nwin) {
            xT[cur ^ 1][sk4 + 0][srow] = vn.x;
            xT[cur ^ 1][sk4 + 1][srow] = vn.y;
            xT[cur ^ 1][sk4 + 2][srow] = vn.z;
            xT[cur ^ 1][sk4 + 3][srow] = vn.w;
            if (w + 2 < nwin)
                vn = *(const float4*)(xsrc + (size_t)(w + 2) * KW);
        }
        __syncthreads();

        // pure SMEM + FMA region: lgkm waits count only s_loads
        const float* wpk = wbase + (size_t)(k0 + w * KW) * 64;
#pragma unroll 4
        for (int k = 0; k < KW; ++k) {
            const float* wk = wpk + (size_t)k * 64;   // uniform -> s_load_x16
#pragma unroll
            for (int j = 0; j < 16; ++j)
                acc[j] = fmaf(xv[k], wk[j], acc[j]);
        }
        cur ^= 1;
    }

    float* zp = zpart + ((size_t)ks * 64 + e0) * N + r0 + lane;
#pragma unroll
    for (int e = 0; e < 16; ++e)
        zp[(size_t)e * N] = acc[e];
}

// ---------------------------------------------------------------------------
// Epilogue: thread = row. Sum K-split partials (fixed order) + bias,
// in-thread top-2 (strict > => lowest index on ties), 3rd-max gap flag,
// softmax, rz row value. All loads coalesced (row = consecutive threads).
// ---------------------------------------------------------------------------
__global__ __launch_bounds__(256)
void epilogue(const float* __restrict__ zpart, const float* __restrict__ b,
              int N, int ks_count,
              float* __restrict__ ts, int* __restrict__ sel,
              float* __restrict__ rzrow,
              int* __restrict__ nflags, int* __restrict__ flaglist)
{
    const int row = blockIdx.x * 256 + threadIdx.x;
    if (row >= N) return;

    float acc[64];
#pragma unroll
    for (int e = 0; e < 64; ++e) acc[e] = b[e];
    for (int ks = 0; ks < ks_count; ++ks) {
        const float* zp = zpart + ((size_t)ks * 64) * N + row;
#pragma unroll
        for (int e = 0; e < 64; ++e) acc[e] += zp[(size_t)e * N];
    }

    float v1 = -3.4e38f, v2 = -3.4e38f;
    int i1 = 0, i2 = 0;
#pragma unroll
    for (int e = 0; e < 64; ++e) {
        const float v = acc[e];
        if (v > v1)      { v2 = v1; i2 = i1; v1 = v; i1 = e; }
        else if (v > v2) { v2 = v;  i2 = e; }
    }
    float m3 = -3.4e38f;
#pragma unroll
    for (int e = 0; e < 64; ++e) {
        const float v = acc[e];
        const bool skip = (e == i1) || (e == i2);
        m3 = skip ? m3 : fmaxf(m3, v);
    }

    float ssum = 0.0f;
#pragma unroll
    for (int e = 0; e < 64; ++e) { acc[e] = expf(acc[e] - v1); ssum += acc[e]; }
    const float inv = 1.0f / ssum;
    float srz = 0.0f;
#pragma unroll
    for (int e = 0; e < 64; ++e) {
        float sc = fminf(fmaxf(acc[e] * inv, EPS_), 1.0f - EPS_);
        srz += sc / (1.0f - sc);
    }

    const float s1 = fminf(fmaxf(inv, EPS_), 1.0f - EPS_);
    const float s2 = fminf(fmaxf(expf(v2 - v1) * inv, EPS_), 1.0f - EPS_);
    ts[row * 2 + 0] = s1;
    ts[row * 2 + 1] = s2;
    sel[row * 2 + 0] = i1;
    sel[row * 2 + 1] = i2;
    rzrow[row] = srz;
    if ((v1 - v2) < MARGIN || (v2 - m3) < MARGIN) {
        const int slot = atomicAdd(nflags, 1);
        flaglist[slot] = row;
    }
}

// ---------------------------------------------------------------------------
// fp64 recompute of flagged near-tie rows. 1024 thr = 64 e x 16 K-slices,
// 4 independent chains of 32 per slice.
// ---------------------------------------------------------------------------
__global__ __launch_bounds__(1024)
void fixup(const float* __restrict__ x, const float* __restrict__ W,
           const float* __restrict__ b, int dim,
           const int* __restrict__ nflags, const int* __restrict__ flaglist,
           float* __restrict__ ts, int* __restrict__ sel)
{
    __shared__ double red[1024];
    const int tid = threadIdx.x;
    const int e = tid & 63;
    const int q = tid >> 6;              // 0..15
    const int nf = *nflags;
    const int slice = dim >> 4;          // 128

    for (int f = blockIdx.x; f < nf; f += gridDim.x) {
        const int row = flaglist[f];
        const float* xr = x + (size_t)row * dim;
        const int k0 = q * slice;
        double a0 = 0.0, a1 = 0.0, a2 = 0.0, a3 = 0.0;
        for (int k = k0; k < k0 + slice; k += 4) {
            a0 = fma((double)xr[k + 0], (double)W[(size_t)(k + 0) * 64 + e], a0);
            a1 = fma((double)xr[k + 1], (double)W[(size_t)(k + 1) * 64 + e], a1);
            a2 = fma((double)xr[k + 2], (double)W[(size_t)(k + 2) * 64 + e], a2);
            a3 = fma((double)xr[k + 3], (double)W[(size_t)(k + 3) * 64 + e], a3);
        }
        red[tid] = (a0 + a1) + (a2 + a3);
        __syncthreads();
        for (int st = 512; st >= 64; st >>= 1) {
            if (tid < st) red[tid] += red[tid + st];
            __syncthreads();
        }
        if (tid < 64) {
            const double z = red[tid] + (double)b[e];
            double v1 = z, v2 = -1e300;
            int i1 = e, i2 = 1 << 30;
#pragma unroll
            for (int m = 1; m < 64; m <<= 1) {
                const double w1 = __shfl_xor(v1, m, 64); const int j1 = __shfl_xor(i1, m, 64);
                const double w2 = __shfl_xor(v2, m, 64); const int j2 = __shfl_xor(i2, m, 64);
                if (betterd(w1, j1, v1, i1)) {
                    double nv2; int ni2;
                    if (betterd(v1, i1, w2, j2)) { nv2 = v1; ni2 = i1; }
                    else                         { nv2 = w2; ni2 = j2; }
                    v1 = w1; i1 = j1; v2 = nv2; i2 = ni2;
                } else if (betterd(w1, j1, v2, i2)) { v2 = w1; i2 = j1; }
            }
            float sl = expf((float)(z - v1));
            float ssum = sl;
#pragma unroll
            for (int m = 1; m < 64; m <<= 1) ssum += __shfl_xor(ssum, m, 64);
            const float inv = 1.0f / ssum;
            if (e == 0) {
                const float s1 = fminf(fmaxf(inv, EPS_), 1.0f - EPS_);
                const float s2 = fminf(fmaxf(expf((float)(v2 - v1)) * inv, EPS_), 1.0f - EPS_);
                ts[row * 2 + 0] = s1;
                ts[row * 2 + 1] = s2;
                sel[row * 2 + 0] = i1;
                sel[row * 2 + 1] = i2;
            }
        }
        __syncthreads();
    }
}

// per-64-slot-chunk expert counts (transposed layout) + global histogram
__global__ void hist_chunks(const int* __restrict__ sel, int nchunks,
                            int* __restrict__ hist, int* __restrict__ cnt2)
{
    __shared__ int cnt[64];
    const int lane = threadIdx.x;   // 64
    const int c = blockIdx.x;
    cnt[lane] = 0;
    __syncthreads();
    const int ex = sel[c * 64 + lane];
    atomicAdd(&cnt[ex], 1);
    __syncthreads();
    cnt2[(size_t)lane * nchunks + c] = cnt[lane];
    if (cnt[lane]) atomicAdd(&hist[lane], cnt[lane]);
}

// per-batch rz sums (deterministic tree)
__global__ void rz_batch(const float* __restrict__ rzrow,
                         const int* __restrict__ bs_p, const int* __restrict__ sl_p,
                         double* __restrict__ bsum)
{
    __shared__ double red[256];
    const int nb = bs_p[0];
    const int seq = sl_p[0];
    for (int bb = blockIdx.x; bb < nb; bb += gridDim.x) {
        double s = 0.0;
        for (int i = threadIdx.x; i < seq; i += 256)
            s += (double)rzrow[(size_t)bb * seq + i];
        red[threadIdx.x] = s;
        __syncthreads();
        for (int st = 128; st > 0; st >>= 1) {
            if (threadIdx.x < st) red[threadIdx.x] += red[threadIdx.x + st];
            __syncthreads();
        }
        if (threadIdx.x == 0) bsum[bb] = red[0];
        __syncthreads();
    }
}

// expert starts (exclusive scan of hist) + out_cnt + rz finalize
__global__ void combine(const int* __restrict__ hist,
                        int* __restrict__ estart,
                        const double* __restrict__ bsum,
                        const int* __restrict__ bs_p,
                        float* __restrict__ out_cnt, float* __restrict__ out_rz)
{
    const int e = threadIdx.x;   // 64
    const int c0 = hist[e];
    int incl = c0;
#pragma unroll
    for (int m = 1; m < 64; m <<= 1) {
        const int w = __shfl_up(incl, m, 64);
        if (e >= m) incl += w;
    }
    estart[e] = incl - c0;
    out_cnt[e] = (float)c0;
    if (e == 0) {
        const int nb = bs_p[0];
        double a = 0.0;
        for (int i = 0; i < nb; ++i) a += log(bsum[i]);
        out_rz[0] = (float)(a / nb);
    }
}

// parallel per-expert scan over chunks
__global__ __launch_bounds__(1024)
void chunk_scan(const int* __restrict__ cnt2, const int* __restrict__ estart,
                int nchunks, int* __restrict__ cbase)
{
    __shared__ int sc[1024];
    const int e = blockIdx.x;    // 64 blocks
    const int t = threadIdx.x;   // 1024
    const int v = (t < nchunks) ? cnt2[(size_t)e * nchunks + t] : 0;
    sc[t] = v;
    __syncthreads();
#pragma unroll
    for (int off = 1; off < 1024; off <<= 1) {
        const int add = (t >= off) ? sc[t - off] : 0;
        __syncthreads();
        sc[t] += add;
        __syncthreads();
    }
    if (t < nchunks)
        cbase[(size_t)t * 64 + e] = estart[e] + sc[t] - v;   // exclusive
}

// stable scatter per 64-slot chunk
__global__ void scatter(const int* __restrict__ sel, const float* __restrict__ ts,
                        const int* __restrict__ cbase,
                        float* __restrict__ out_sc, float* __restrict__ out_idx)
{
    __shared__ int shx[64];
    const int lane = threadIdx.x;   // 64
    const int c = blockIdx.x;
    const int idx = c * 64 + lane;
    const int ex = sel[idx];
    shx[lane] = ex;
    __syncthreads();
    int pre = 0;
#pragma unroll
    for (int j = 0; j < 64; ++j) pre += (int)((j < lane) && (shx[j] == ex));
    const int pos = cbase[c * 64 + ex] + pre;
    out_sc[pos]  = ts[idx];
    out_idx[pos] = (float)(idx >> 1);
}

extern "C" void kernel_launch(void* const* d_in, const int* in_sizes, int n_in,
                              void* d_out, int out_size, void* d_ws, size_t ws_size,
                              hipStream_t stream)
{
    const float* x = (const float*)d_in[0];
    const float* W = (const float*)d_in[1];
    const float* b = (const float*)d_in[2];
    const int* bs_p = (const int*)d_in[3];
    const int* sl_p = (const int*)d_in[4];

    const int E   = in_sizes[2];           // 64
    const int dim = in_sizes[1] / E;       // 2048
    const int N   = in_sizes[0] / dim;     // 16384
    const int total = N * 2;               // slots
    const int nchunks = total / 64;        // 512

    char* ws = (char*)d_ws;
    size_t off = 0;
    int*    hist     = (int*)(ws + off); off += 256;
    double* bsum     = (double*)(ws + off); off += 512;
    int*    nflags   = (int*)(ws + off); off += 256;
    int*    estart   = (int*)(ws + off); off += 256;
    float*  ts       = (float*)(ws + off); off += (size_t)total * 4;
    int*    sel      = (int*)(ws + off); off += (size_t)total * 4;
    int*    flaglist = (int*)(ws + off); off += (size_t)N * 4;
    float*  rzrow    = (float*)(ws + off); off += (size_t)N * 4;
    int*    cnt2     = (int*)(ws + off); off += (size_t)nchunks * 64 * 4;
    int*    cbase    = (int*)(ws + off); off += (size_t)nchunks * 64 * 4;

    // pick largest ksplit whose zpart fits the workspace
    int ksplit = 8;
    while (ksplit > 1 &&
           off + (size_t)ksplit * N * 64 * sizeof(float) > ws_size)
        ksplit >>= 1;
    float* zpart = (float*)(ws + off);

    float* out_sc  = (float*)d_out;
    float* out_idx = out_sc + total;
    float* out_cnt = out_idx + total;
    float* out_rz  = out_cnt + E;

    hipMemsetAsync(ws, 0, 1280, stream);

    const int rgs = N / 64;  // 256 row groups
    hipLaunchKernelGGL(gemm_rows, dim3(rgs * ksplit), dim3(256), 0, stream,
                       x, W, dim, N, ksplit, rgs, zpart);
    hipLaunchKernelGGL(epilogue, dim3(N / 256), dim3(256), 0, stream,
                       zpart, b, N, ksplit, ts, sel, rzrow, nflags, flaglist);
    hipLaunchKernelGGL(fixup, dim3(512), dim3(1024), 0, stream,
                       x, W, b, dim, nflags, flaglist, ts, sel);
    hipLaunchKernelGGL(hist_chunks, dim3(nchunks), dim3(64), 0, stream,
                       sel, nchunks, hist, cnt2);
    hipLaunchKernelGGL(rz_batch, dim3(64), dim3(256), 0, stream,
                       rzrow, bs_p, sl_p, bsum);
    hipLaunchKernelGGL(combine, dim3(1), dim3(64), 0, stream,
                       hist, estart, bsum, bs_p, out_cnt, out_rz);
    hipLaunchKernelGGL(chunk_scan, dim3(64), dim3(1024), 0, stream,
                       cnt2, estart, nchunks, cbase);
    hipLaunchKernelGGL(scatter, dim3(nchunks), dim3(64), 0, stream,
                       sel, ts, cbase, out_sc, out_idx);
}

// Round 10
// 110.095 us; speedup vs baseline: 1.7470x; 1.7470x over previous
//
#include <hip/hip_runtime.h>
#include <math.h>

#define EPS_ 1e-10f
#define MARGIN 4e-3f

typedef __attribute__((ext_vector_type(8))) short sh8;
typedef __attribute__((ext_vector_type(4))) float fx4;

__device__ __forceinline__ bool betterf(float v, int i, float w, int j) {
    return (v > w) || (v == w && i < j);
}
__device__ __forceinline__ bool betterd(double v, int i, double w, int j) {
    return (v > w) || (v == w && i < j);
}
__device__ __forceinline__ unsigned short f2bf(float f) {   // RNE
    unsigned u = __float_as_uint(f);
    u += 0x7fffu + ((u >> 16) & 1u);
    return (unsigned short)(u >> 16);
}
__device__ __forceinline__ float bf2f(unsigned short h) {
    return __uint_as_float(((unsigned)h) << 16);
}

struct U2x2 { uint2 lo, hi; };

// ---------------------------------------------------------------------------
// One-time W conversion into B-fragment layout, bf16 hi/lo.
// Fragment slot (s,t,hl): 64 lanes x 8 bf16 (1KB). lane l = n + 16*b holds
// W[k = s*32 + b*8 + j][e = t*16 + n], j=0..7.
// wf[( (s*4+t)*2 + hl )*512 + l*8 + j]
// ---------------------------------------------------------------------------
__global__ __launch_bounds__(256)
void wconv(const float* __restrict__ W, unsigned short* __restrict__ wf)
{
    const int gid = blockIdx.x * 256 + threadIdx.x;   // 131072 = 2048*64
    const int e = gid & 63, k = gid >> 6;
    const int s = k >> 5, kk = k & 31, bq = kk >> 3, j = kk & 7;
    const int t = e >> 4, n = e & 15;
    const int l = n + 16 * bq;
    const float w = W[(size_t)k * 64 + e];
    const unsigned short hi = f2bf(w);
    const unsigned short lo = f2bf(w - bf2f(hi));
    const size_t base = ((size_t)s * 4 + t) * 2;
    wf[(base + 0) * 512 + l * 8 + j] = hi;
    wf[(base + 1) * 512 + l * 8 + j] = lo;
}

// ---------------------------------------------------------------------------
// Fused router GEMM: 256 blocks x 256 thr (4 waves). Wave = 16 rows x 64
// experts, full K via mfma_f32_16x16x32_bf16, bf16x3 emulation
// (xh*Wh + xh*Wl + xl*Wh), fp32 accumulate in fixed order.
// Per 32-k window: x[64][32] converted to bf16 hi/lo in LDS (dbuf),
// W-fragments staged LDS (dbuf). Epilogue fused: C layout col=lane&15,
// row=(lane>>4)*4+reg; top-2 via width-16 butterfly.
// ---------------------------------------------------------------------------
#define ROWPAD 68
__global__ __launch_bounds__(256)
void gemm_fused(const float* __restrict__ x, const unsigned short* __restrict__ wfg,
                const float* __restrict__ b, int dim, int N,
                float* __restrict__ ts, int* __restrict__ sel,
                float* __restrict__ rzrow,
                int* __restrict__ nflags, int* __restrict__ flaglist)
{
    __shared__ unsigned short xh[2][64][ROWPAD];
    __shared__ unsigned short xl[2][64][ROWPAD];
    __shared__ unsigned short wfl[2][4096];   // one K-step: 4 tiles x 2 hl x 512

    const int tid  = threadIdx.x;
    const int lane = tid & 63;
    const int wv   = tid >> 6;
    const int r0   = blockIdx.x * 64;
    const int nstep = dim / 32;               // 64

    // staging mapping: thread = (row, 8-col chunk)
    const int srow = tid >> 2;                // 0..63
    const int sk   = (tid & 3) * 8;           // 0,8,16,24

    const float* xp = x + (size_t)(r0 + srow) * dim + sk;

    fx4 acc[4] = {};

    // ---- prologue: stage step 0 ----
    {
        const float4 xa = *(const float4*)(xp);
        const float4 xb = *(const float4*)(xp + 4);
        const int4* wsrc = (const int4*)(wfg);
        const int4 wa = wsrc[tid * 2], wb = wsrc[tid * 2 + 1];
        unsigned short h[8], l[8];
        const float v[8] = {xa.x, xa.y, xa.z, xa.w, xb.x, xb.y, xb.z, xb.w};
#pragma unroll
        for (int c = 0; c < 8; ++c) { h[c] = f2bf(v[c]); l[c] = f2bf(v[c] - bf2f(h[c])); }
        uint2 h0, h1, l0, l1;
        h0.x = h[0] | ((unsigned)h[1] << 16); h0.y = h[2] | ((unsigned)h[3] << 16);
        h1.x = h[4] | ((unsigned)h[5] << 16); h1.y = h[6] | ((unsigned)h[7] << 16);
        l0.x = l[0] | ((unsigned)l[1] << 16); l0.y = l[2] | ((unsigned)l[3] << 16);
        l1.x = l[4] | ((unsigned)l[5] << 16); l1.y = l[6] | ((unsigned)l[7] << 16);
        *(uint2*)&xh[0][srow][sk]     = h0;
        *(uint2*)&xh[0][srow][sk + 4] = h1;
        *(uint2*)&xl[0][srow][sk]     = l0;
        *(uint2*)&xl[0][srow][sk + 4] = l1;
        *(int4*)&wfl[0][tid * 16]     = wa;
        *(int4*)&wfl[0][tid * 16 + 8] = wb;
    }
    __syncthreads();

    const int m  = lane & 15;
    const int bq = lane >> 4;

    for (int w = 0; w < nstep; ++w) {
        const int cur = w & 1;

        // issue next-step global loads early (hide HBM under compute)
        float4 xa, xb; int4 wa, wb;
        if (w + 1 < nstep) {
            xa = *(const float4*)(xp + (size_t)(w + 1) * 32);
            xb = *(const float4*)(xp + (size_t)(w + 1) * 32 + 4);
            const int4* wsrc = (const int4*)(wfg + (size_t)(w + 1) * 4096);
            wa = wsrc[tid * 2]; wb = wsrc[tid * 2 + 1];
        }

        // ---- compute step w ----
        U2x2 au, bu;
        const unsigned short* ah = &xh[cur][wv * 16 + m][bq * 8];
        const unsigned short* al = &xl[cur][wv * 16 + m][bq * 8];
        au.lo = *(const uint2*)ah; au.hi = *(const uint2*)(ah + 4);
        bu.lo = *(const uint2*)al; bu.hi = *(const uint2*)(al + 4);
        const sh8 ahi = __builtin_bit_cast(sh8, au);
        const sh8 alo = __builtin_bit_cast(sh8, bu);
#pragma unroll
        for (int t = 0; t < 4; ++t) {
            const sh8 bhi = __builtin_bit_cast(sh8,
                *(const int4*)&wfl[cur][(t * 2 + 0) * 512 + lane * 8]);
            const sh8 blo = __builtin_bit_cast(sh8,
                *(const int4*)&wfl[cur][(t * 2 + 1) * 512 + lane * 8]);
            acc[t] = __builtin_amdgcn_mfma_f32_16x16x32_bf16(ahi, bhi, acc[t], 0, 0, 0);
            acc[t] = __builtin_amdgcn_mfma_f32_16x16x32_bf16(ahi, blo, acc[t], 0, 0, 0);
            acc[t] = __builtin_amdgcn_mfma_f32_16x16x32_bf16(alo, bhi, acc[t], 0, 0, 0);
        }

        // ---- stage step w+1 into other buffer ----
        if (w + 1 < nstep) {
            const int nb2 = cur ^ 1;
            unsigned short h[8], l[8];
            const float v[8] = {xa.x, xa.y, xa.z, xa.w, xb.x, xb.y, xb.z, xb.w};
#pragma unroll
            for (int c = 0; c < 8; ++c) { h[c] = f2bf(v[c]); l[c] = f2bf(v[c] - bf2f(h[c])); }
            uint2 h0, h1, l0, l1;
            h0.x = h[0] | ((unsigned)h[1] << 16); h0.y = h[2] | ((unsigned)h[3] << 16);
            h1.x = h[4] | ((unsigned)h[5] << 16); h1.y = h[6] | ((unsigned)h[7] << 16);
            l0.x = l[0] | ((unsigned)l[1] << 16); l0.y = l[2] | ((unsigned)l[3] << 16);
            l1.x = l[4] | ((unsigned)l[5] << 16); l1.y = l[6] | ((unsigned)l[7] << 16);
            *(uint2*)&xh[nb2][srow][sk]     = h0;
            *(uint2*)&xh[nb2][srow][sk + 4] = h1;
            *(uint2*)&xl[nb2][srow][sk]     = l0;
            *(uint2*)&xl[nb2][srow][sk + 4] = l1;
            *(int4*)&wfl[nb2][tid * 16]     = wa;
            *(int4*)&wfl[nb2][tid * 16 + 8] = wb;
        }
        __syncthreads();
    }

    // ---- fused epilogue ----
    // C layout: col(e-in-tile) = lane&15, row-in-16 = (lane>>4)*4 + reg
    const int n = lane & 15;
    const int g = lane >> 4;
    float bb[4];
#pragma unroll
    for (int t = 0; t < 4; ++t) bb[t] = b[t * 16 + n];

#pragma unroll
    for (int i = 0; i < 4; ++i) {
        const int row = r0 + wv * 16 + g * 4 + i;
        float z[4];
#pragma unroll
        for (int t = 0; t < 4; ++t) z[t] = acc[t][i] + bb[t];

        // local top2 over this lane's 4 experts (e = t*16 + n, ascending)
        float v1 = -3.4e38f, v2 = -3.4e38f;
        int i1 = 1 << 30, i2 = 1 << 30;
#pragma unroll
        for (int t = 0; t < 4; ++t) {
            const float v = z[t];
            const int e = t * 16 + n;
            if (v > v1)      { v2 = v1; i2 = i1; v1 = v; i1 = e; }
            else if (v > v2) { v2 = v;  i2 = e; }
        }
        // width-16 butterfly merge (stays within the lane>>4 group)
#pragma unroll
        for (int mm = 1; mm < 16; mm <<= 1) {
            const float w1 = __shfl_xor(v1, mm, 16); const int j1 = __shfl_xor(i1, mm, 16);
            const float w2 = __shfl_xor(v2, mm, 16); const int j2 = __shfl_xor(i2, mm, 16);
            if (betterf(w1, j1, v1, i1)) {
                float nv2; int ni2;
                if (betterf(v1, i1, w2, j2)) { nv2 = v1; ni2 = i1; }
                else                         { nv2 = w2; ni2 = j2; }
                v1 = w1; i1 = j1; v2 = nv2; i2 = ni2;
            } else if (betterf(w1, j1, v2, i2)) { v2 = w1; i2 = j1; }
        }

        // third max
        float m3 = -3.4e38f;
#pragma unroll
        for (int t = 0; t < 4; ++t) {
            const int e = t * 16 + n;
            const bool skip = (e == i1) || (e == i2);
            m3 = skip ? m3 : fmaxf(m3, z[t]);
        }
#pragma unroll
        for (int mm = 1; mm < 16; mm <<= 1) m3 = fmaxf(m3, __shfl_xor(m3, mm, 16));

        // softmax + rz
        float sloc[4], ssum = 0.0f;
#pragma unroll
        for (int t = 0; t < 4; ++t) { sloc[t] = expf(z[t] - v1); ssum += sloc[t]; }
#pragma unroll
        for (int mm = 1; mm < 16; mm <<= 1) ssum += __shfl_xor(ssum, mm, 16);
        const float inv = 1.0f / ssum;
        float srz = 0.0f;
#pragma unroll
        for (int t = 0; t < 4; ++t) {
            float sc = fminf(fmaxf(sloc[t] * inv, EPS_), 1.0f - EPS_);
            srz += sc / (1.0f - sc);
        }
#pragma unroll
        for (int mm = 1; mm < 16; mm <<= 1) srz += __shfl_xor(srz, mm, 16);

        if (n == 0) {
            const float s1 = fminf(fmaxf(inv, EPS_), 1.0f - EPS_);
            const float s2 = fminf(fmaxf(expf(v2 - v1) * inv, EPS_), 1.0f - EPS_);
            ts[row * 2 + 0] = s1;
            ts[row * 2 + 1] = s2;
            sel[row * 2 + 0] = i1;
            sel[row * 2 + 1] = i2;
            rzrow[row] = srz;
            if ((v1 - v2) < MARGIN || (v2 - m3) < MARGIN) {
                const int slot = atomicAdd(nflags, 1);
                flaglist[slot] = row;
            }
        }
    }
}

// ---------------------------------------------------------------------------
// fp64 recompute of flagged near-tie rows. 1024 thr = 64 e x 16 K-slices.
// ---------------------------------------------------------------------------
__global__ __launch_bounds__(1024)
void fixup(const float* __restrict__ x, const float* __restrict__ W,
           const float* __restrict__ b, int dim,
           const int* __restrict__ nflags, const int* __restrict__ flaglist,
           float* __restrict__ ts, int* __restrict__ sel)
{
    __shared__ double red[1024];
    const int tid = threadIdx.x;
    const int e = tid & 63;
    const int q = tid >> 6;              // 0..15
    const int nf = *nflags;
    const int slice = dim >> 4;          // 128

    for (int f = blockIdx.x; f < nf; f += gridDim.x) {
        const int row = flaglist[f];
        const float* xr = x + (size_t)row * dim;
        const int k0 = q * slice;
        double a0 = 0.0, a1 = 0.0, a2 = 0.0, a3 = 0.0;
        for (int k = k0; k < k0 + slice; k += 4) {
            a0 = fma((double)xr[k + 0], (double)W[(size_t)(k + 0) * 64 + e], a0);
            a1 = fma((double)xr[k + 1], (double)W[(size_t)(k + 1) * 64 + e], a1);
            a2 = fma((double)xr[k + 2], (double)W[(size_t)(k + 2) * 64 + e], a2);
            a3 = fma((double)xr[k + 3], (double)W[(size_t)(k + 3) * 64 + e], a3);
        }
        red[tid] = (a0 + a1) + (a2 + a3);
        __syncthreads();
        for (int st = 512; st >= 64; st >>= 1) {
            if (tid < st) red[tid] += red[tid + st];
            __syncthreads();
        }
        if (tid < 64) {
            const double z = red[tid] + (double)b[e];
            double v1 = z, v2 = -1e300;
            int i1 = e, i2 = 1 << 30;
#pragma unroll
            for (int mm = 1; mm < 64; mm <<= 1) {
                const double w1 = __shfl_xor(v1, mm, 64); const int j1 = __shfl_xor(i1, mm, 64);
                const double w2 = __shfl_xor(v2, mm, 64); const int j2 = __shfl_xor(i2, mm, 64);
                if (betterd(w1, j1, v1, i1)) {
                    double nv2; int ni2;
                    if (betterd(v1, i1, w2, j2)) { nv2 = v1; ni2 = i1; }
                    else                         { nv2 = w2; ni2 = j2; }
                    v1 = w1; i1 = j1; v2 = nv2; i2 = ni2;
                } else if (betterd(w1, j1, v2, i2)) { v2 = w1; i2 = j1; }
            }
            float sl = expf((float)(z - v1));
            float ssum = sl;
#pragma unroll
            for (int mm = 1; mm < 64; mm <<= 1) ssum += __shfl_xor(ssum, mm, 64);
            const float inv = 1.0f / ssum;
            if (e == 0) {
                const float s1 = fminf(fmaxf(inv, EPS_), 1.0f - EPS_);
                const float s2 = fminf(fmaxf(expf((float)(v2 - v1)) * inv, EPS_), 1.0f - EPS_);
                ts[row * 2 + 0] = s1;
                ts[row * 2 + 1] = s2;
                sel[row * 2 + 0] = i1;
                sel[row * 2 + 1] = i2;
            }
        }
        __syncthreads();
    }
}

// per-64-slot-chunk expert counts (transposed layout) + global histogram
__global__ void hist_chunks(const int* __restrict__ sel, int nchunks,
                            int* __restrict__ hist, int* __restrict__ cnt2)
{
    __shared__ int cnt[64];
    const int lane = threadIdx.x;   // 64
    const int c = blockIdx.x;
    cnt[lane] = 0;
    __syncthreads();
    const int ex = sel[c * 64 + lane];
    atomicAdd(&cnt[ex], 1);
    __syncthreads();
    cnt2[(size_t)lane * nchunks + c] = cnt[lane];
    if (cnt[lane]) atomicAdd(&hist[lane], cnt[lane]);
}

// per-batch rz sums (deterministic tree)
__global__ void rz_batch(const float* __restrict__ rzrow,
                         const int* __restrict__ bs_p, const int* __restrict__ sl_p,
                         double* __restrict__ bsum)
{
    __shared__ double red[256];
    const int nb = bs_p[0];
    const int seq = sl_p[0];
    for (int bb = blockIdx.x; bb < nb; bb += gridDim.x) {
        double s = 0.0;
        for (int i = threadIdx.x; i < seq; i += 256)
            s += (double)rzrow[(size_t)bb * seq + i];
        red[threadIdx.x] = s;
        __syncthreads();
        for (int st = 128; st > 0; st >>= 1) {
            if (threadIdx.x < st) red[threadIdx.x] += red[threadIdx.x + st];
            __syncthreads();
        }
        if (threadIdx.x == 0) bsum[bb] = red[0];
        __syncthreads();
    }
}

// expert starts (exclusive scan of hist) + out_cnt + rz finalize
__global__ void combine(const int* __restrict__ hist,
                        int* __restrict__ estart,
                        const double* __restrict__ bsum,
                        const int* __restrict__ bs_p,
                        float* __restrict__ out_cnt, float* __restrict__ out_rz)
{
    const int e = threadIdx.x;   // 64
    const int c0 = hist[e];
    int incl = c0;
#pragma unroll
    for (int mm = 1; mm < 64; mm <<= 1) {
        const int w = __shfl_up(incl, mm, 64);
        if (e >= mm) incl += w;
    }
    estart[e] = incl - c0;
    out_cnt[e] = (float)c0;
    if (e == 0) {
        const int nb = bs_p[0];
        double a = 0.0;
        for (int i = 0; i < nb; ++i) a += log(bsum[i]);
        out_rz[0] = (float)(a / nb);
    }
}

// parallel per-expert scan over chunks
__global__ __launch_bounds__(1024)
void chunk_scan(const int* __restrict__ cnt2, const int* __restrict__ estart,
                int nchunks, int* __restrict__ cbase)
{
    __shared__ int sc[1024];
    const int e = blockIdx.x;    // 64 blocks
    const int t = threadIdx.x;   // 1024
    const int v = (t < nchunks) ? cnt2[(size_t)e * nchunks + t] : 0;
    sc[t] = v;
    __syncthreads();
#pragma unroll
    for (int off = 1; off < 1024; off <<= 1) {
        const int add = (t >= off) ? sc[t - off] : 0;
        __syncthreads();
        sc[t] += add;
        __syncthreads();
    }
    if (t < nchunks)
        cbase[(size_t)t * 64 + e] = estart[e] + sc[t] - v;   // exclusive
}

// stable scatter per 64-slot chunk
__global__ void scatter(const int* __restrict__ sel, const float* __restrict__ ts,
                        const int* __restrict__ cbase,
                        float* __restrict__ out_sc, float* __restrict__ out_idx)
{
    __shared__ int shx[64];
    const int lane = threadIdx.x;   // 64
    const int c = blockIdx.x;
    const int idx = c * 64 + lane;
    const int ex = sel[idx];
    shx[lane] = ex;
    __syncthreads();
    int pre = 0;
#pragma unroll
    for (int j = 0; j < 64; ++j) pre += (int)((j < lane) && (shx[j] == ex));
    const int pos = cbase[c * 64 + ex] + pre;
    out_sc[pos]  = ts[idx];
    out_idx[pos] = (float)(idx >> 1);
}

extern "C" void kernel_launch(void* const* d_in, const int* in_sizes, int n_in,
                              void* d_out, int out_size, void* d_ws, size_t ws_size,
                              hipStream_t stream)
{
    const float* x = (const float*)d_in[0];
    const float* W = (const float*)d_in[1];
    const float* b = (const float*)d_in[2];
    const int* bs_p = (const int*)d_in[3];
    const int* sl_p = (const int*)d_in[4];

    const int E   = in_sizes[2];           // 64
    const int dim = in_sizes[1] / E;       // 2048
    const int N   = in_sizes[0] / dim;     // 16384
    const int total = N * 2;               // slots
    const int nchunks = total / 64;        // 512

    char* ws = (char*)d_ws;
    size_t off = 0;
    int*    hist     = (int*)(ws + off); off += 256;
    double* bsum     = (double*)(ws + off); off += 512;
    int*    nflags   = (int*)(ws + off); off += 256;
    int*    estart   = (int*)(ws + off); off += 256;
    float*  ts       = (float*)(ws + off); off += (size_t)total * 4;
    int*    sel      = (int*)(ws + off); off += (size_t)total * 4;
    int*    flaglist = (int*)(ws + off); off += (size_t)N * 4;
    float*  rzrow    = (float*)(ws + off); off += (size_t)N * 4;
    int*    cnt2     = (int*)(ws + off); off += (size_t)nchunks * 64 * 4;
    int*    cbase    = (int*)(ws + off); off += (size_t)nchunks * 64 * 4;
    unsigned short* wfg = (unsigned short*)(ws + off); off += (size_t)dim * 64 * 2 * 2;

    float* out_sc  = (float*)d_out;
    float* out_idx = out_sc + total;
    float* out_cnt = out_idx + total;
    float* out_rz  = out_cnt + E;

    hipMemsetAsync(ws, 0, 1280, stream);

    hipLaunchKernelGGL(wconv, dim3(dim * 64 / 256), dim3(256), 0, stream, W, wfg);
    hipLaunchKernelGGL(gemm_fused, dim3(N / 64), dim3(256), 0, stream,
                       x, wfg, b, dim, N, ts, sel, rzrow, nflags, flaglist);
    hipLaunchKernelGGL(fixup, dim3(512), dim3(1024), 0, stream,
                       x, W, b, dim, nflags, flaglist, ts, sel);
    hipLaunchKernelGGL(hist_chunks, dim3(nchunks), dim3(64), 0, stream,
                       sel, nchunks, hist, cnt2);
    hipLaunchKernelGGL(rz_batch, dim3(64), dim3(256), 0, stream,
                       rzrow, bs_p, sl_p, bsum);
    hipLaunchKernelGGL(combine, dim3(1), dim3(64), 0, stream,
                       hist, estart, bsum, bs_p, out_cnt, out_rz);
    hipLaunchKernelGGL(chunk_scan, dim3(64), dim3(1024), 0, stream,
                       cnt2, estart, nchunks, cbase);
    hipLaunchKernelGGL(scatter, dim3(nchunks), dim3(64), 0, stream,
                       sel, ts, cbase, out_sc, out_idx);
}

// Round 11
// 102.388 us; speedup vs baseline: 1.8785x; 1.0753x over previous
//
#include <hip/hip_runtime.h>
#include <math.h>

#define EPS_ 1e-10f
#define MARGIN 4e-3f

typedef __attribute__((ext_vector_type(8))) short sh8;
typedef __attribute__((ext_vector_type(4))) float fx4;

__device__ __forceinline__ bool betterf(float v, int i, float w, int j) {
    return (v > w) || (v == w && i < j);
}
__device__ __forceinline__ bool betterd(double v, int i, double w, int j) {
    return (v > w) || (v == w && i < j);
}
__device__ __forceinline__ unsigned short f2bf(float f) {   // RNE
    unsigned u = __float_as_uint(f);
    u += 0x7fffu + ((u >> 16) & 1u);
    return (unsigned short)(u >> 16);
}
__device__ __forceinline__ float bf2f(unsigned short h) {
    return __uint_as_float(((unsigned)h) << 16);
}
__device__ __forceinline__ void cvt8(const float4 a, const float4 c, sh8& hi, sh8& lo) {
    const float v[8] = {a.x, a.y, a.z, a.w, c.x, c.y, c.z, c.w};
#pragma unroll
    for (int j = 0; j < 8; ++j) {
        const unsigned short h = f2bf(v[j]);
        hi[j] = (short)h;
        lo[j] = (short)f2bf(v[j] - bf2f(h));
    }
}

// ---------------------------------------------------------------------------
// One-time W conversion into B-fragment layout, bf16 hi/lo (layout verified
// by R10 pass). wf[((s*4+t)*2+hl)*512 + l*8 + j]; lane l=n+16*bq holds
// W[k=s*32+bq*8+j][e=t*16+n].
// ---------------------------------------------------------------------------
__global__ __launch_bounds__(256)
void wconv(const float* __restrict__ W, unsigned short* __restrict__ wf)
{
    const int gid = blockIdx.x * 256 + threadIdx.x;   // dim*64
    const int e = gid & 63, k = gid >> 6;
    const int s = k >> 5, kk = k & 31, bq = kk >> 3, j = kk & 7;
    const int t = e >> 4, n = e & 15;
    const int l = n + 16 * bq;
    const float w = W[(size_t)k * 64 + e];
    const unsigned short hi = f2bf(w);
    const unsigned short lo = f2bf(w - bf2f(hi));
    const size_t base = ((size_t)s * 4 + t) * 2;
    wf[(base + 0) * 512 + l * 8 + j] = hi;
    wf[(base + 1) * 512 + l * 8 + j] = lo;
}

// ---------------------------------------------------------------------------
// Fused MFMA router: block = 256 thr = 4 waves over the SAME 16 rows,
// each wave one K-slice (dim/4). A-fragments loaded DIRECTLY from global x
// (lane m,q reads x[r0+m][k0+w*32+q*8..+8] as 2 float4 — 16x64B segments),
// converted to bf16 hi/lo in registers. B-fragments read coalesced from the
// pre-converted wfg (L2-hot). No LDS / barriers in the K loop. One final
// padded-LDS reduce (fixed order) + fused epilogue on wave 0.
// Grid = N/16 = 1024 blocks -> 4 blocks/CU, 4 waves/SIMD.
// ---------------------------------------------------------------------------
#define NKS 4
__global__ __launch_bounds__(256, 4)
void gemm_mfma(const float* __restrict__ x, const unsigned short* __restrict__ wfg,
               const float* __restrict__ b, int dim, int N,
               float* __restrict__ ts, int* __restrict__ sel,
               float* __restrict__ rzrow,
               int* __restrict__ nflags, int* __restrict__ flaglist)
{
    __shared__ float red[3][64][17];   // stride 17 -> conflict-free b32

    const int tid  = threadIdx.x;
    const int lane = tid & 63;
    const int wv   = tid >> 6;                // K-slice index
    const int r0   = blockIdx.x * 16;
    const int kslice = dim / NKS;             // 512
    const int k0   = wv * kslice;
    const int nstep = kslice / 32;            // 16

    const int m = lane & 15;
    const int q = lane >> 4;

    fx4 acc[4] = {};

    const float* xp = x + (size_t)(r0 + m) * dim + k0 + q * 8;
    const unsigned short* wbase = wfg + ((size_t)(k0 / 32) * 4096) + lane * 8;

    float4 xa = *(const float4*)xp;
    float4 xb = *(const float4*)(xp + 4);

    for (int w = 0; w < nstep; ++w) {
        sh8 ahi, alo;
        cvt8(xa, xb, ahi, alo);

        // prefetch next step's x while MFMAs run
        if (w + 1 < nstep) {
            xa = *(const float4*)(xp + (size_t)(w + 1) * 32);
            xb = *(const float4*)(xp + (size_t)(w + 1) * 32 + 4);
        }

        const unsigned short* wk = wbase + (size_t)w * 4096;
        sh8 bhi[4], blo[4];
#pragma unroll
        for (int t = 0; t < 4; ++t) {
            bhi[t] = __builtin_bit_cast(sh8, *(const int4*)(wk + (t * 2 + 0) * 512));
            blo[t] = __builtin_bit_cast(sh8, *(const int4*)(wk + (t * 2 + 1) * 512));
        }
        // phase-major: 4 independent acc chains per phase
#pragma unroll
        for (int t = 0; t < 4; ++t)
            acc[t] = __builtin_amdgcn_mfma_f32_16x16x32_bf16(ahi, bhi[t], acc[t], 0, 0, 0);
#pragma unroll
        for (int t = 0; t < 4; ++t)
            acc[t] = __builtin_amdgcn_mfma_f32_16x16x32_bf16(ahi, blo[t], acc[t], 0, 0, 0);
#pragma unroll
        for (int t = 0; t < 4; ++t)
            acc[t] = __builtin_amdgcn_mfma_f32_16x16x32_bf16(alo, bhi[t], acc[t], 0, 0, 0);
    }

    // cross-wave K reduce (fixed order -> deterministic)
    if (wv > 0) {
#pragma unroll
        for (int t = 0; t < 4; ++t)
#pragma unroll
            for (int i = 0; i < 4; ++i)
                red[wv - 1][lane][t * 4 + i] = acc[t][i];
    }
    __syncthreads();
    if (wv != 0) return;

#pragma unroll
    for (int s = 0; s < 3; ++s)
#pragma unroll
        for (int t = 0; t < 4; ++t)
#pragma unroll
            for (int i = 0; i < 4; ++i)
                acc[t][i] += red[s][lane][t * 4 + i];

    // ---- fused epilogue (C layout: col=lane&15, row-in-16=(lane>>4)*4+i) ----
    const int n = lane & 15;
    const int g = lane >> 4;
    float bb[4];
#pragma unroll
    for (int t = 0; t < 4; ++t) bb[t] = b[t * 16 + n];

#pragma unroll
    for (int i = 0; i < 4; ++i) {
        const int row = r0 + g * 4 + i;
        float z[4];
#pragma unroll
        for (int t = 0; t < 4; ++t) z[t] = acc[t][i] + bb[t];

        float v1 = -3.4e38f, v2 = -3.4e38f;
        int i1 = 1 << 30, i2 = 1 << 30;
#pragma unroll
        for (int t = 0; t < 4; ++t) {
            const float v = z[t];
            const int e = t * 16 + n;
            if (v > v1)      { v2 = v1; i2 = i1; v1 = v; i1 = e; }
            else if (v > v2) { v2 = v;  i2 = e; }
        }
#pragma unroll
        for (int mm = 1; mm < 16; mm <<= 1) {
            const float w1 = __shfl_xor(v1, mm, 16); const int j1 = __shfl_xor(i1, mm, 16);
            const float w2 = __shfl_xor(v2, mm, 16); const int j2 = __shfl_xor(i2, mm, 16);
            if (betterf(w1, j1, v1, i1)) {
                float nv2; int ni2;
                if (betterf(v1, i1, w2, j2)) { nv2 = v1; ni2 = i1; }
                else                         { nv2 = w2; ni2 = j2; }
                v1 = w1; i1 = j1; v2 = nv2; i2 = ni2;
            } else if (betterf(w1, j1, v2, i2)) { v2 = w1; i2 = j1; }
        }

        float m3 = -3.4e38f;
#pragma unroll
        for (int t = 0; t < 4; ++t) {
            const int e = t * 16 + n;
            const bool skip = (e == i1) || (e == i2);
            m3 = skip ? m3 : fmaxf(m3, z[t]);
        }
#pragma unroll
        for (int mm = 1; mm < 16; mm <<= 1) m3 = fmaxf(m3, __shfl_xor(m3, mm, 16));

        float sloc[4], ssum = 0.0f;
#pragma unroll
        for (int t = 0; t < 4; ++t) { sloc[t] = expf(z[t] - v1); ssum += sloc[t]; }
#pragma unroll
        for (int mm = 1; mm < 16; mm <<= 1) ssum += __shfl_xor(ssum, mm, 16);
        const float inv = 1.0f / ssum;
        float srz = 0.0f;
#pragma unroll
        for (int t = 0; t < 4; ++t) {
            float sc = fminf(fmaxf(sloc[t] * inv, EPS_), 1.0f - EPS_);
            srz += sc / (1.0f - sc);
        }
#pragma unroll
        for (int mm = 1; mm < 16; mm <<= 1) srz += __shfl_xor(srz, mm, 16);

        if (n == 0) {
            const float s1 = fminf(fmaxf(inv, EPS_), 1.0f - EPS_);
            const float s2 = fminf(fmaxf(expf(v2 - v1) * inv, EPS_), 1.0f - EPS_);
            ts[row * 2 + 0] = s1;
            ts[row * 2 + 1] = s2;
            sel[row * 2 + 0] = i1;
            sel[row * 2 + 1] = i2;
            rzrow[row] = srz;
            if ((v1 - v2) < MARGIN || (v2 - m3) < MARGIN) {
                const int slot = atomicAdd(nflags, 1);
                flaglist[slot] = row;
            }
        }
    }
}

// ---------------------------------------------------------------------------
// fp64 recompute of flagged near-tie rows. 1024 thr = 64 e x 16 K-slices.
// ---------------------------------------------------------------------------
__global__ __launch_bounds__(1024)
void fixup(const float* __restrict__ x, const float* __restrict__ W,
           const float* __restrict__ b, int dim,
           const int* __restrict__ nflags, const int* __restrict__ flaglist,
           float* __restrict__ ts, int* __restrict__ sel)
{
    __shared__ double red[1024];
    const int tid = threadIdx.x;
    const int e = tid & 63;
    const int q = tid >> 6;              // 0..15
    const int nf = *nflags;
    const int slice = dim >> 4;          // 128

    for (int f = blockIdx.x; f < nf; f += gridDim.x) {
        const int row = flaglist[f];
        const float* xr = x + (size_t)row * dim;
        const int k0 = q * slice;
        double a0 = 0.0, a1 = 0.0, a2 = 0.0, a3 = 0.0;
        for (int k = k0; k < k0 + slice; k += 4) {
            a0 = fma((double)xr[k + 0], (double)W[(size_t)(k + 0) * 64 + e], a0);
            a1 = fma((double)xr[k + 1], (double)W[(size_t)(k + 1) * 64 + e], a1);
            a2 = fma((double)xr[k + 2], (double)W[(size_t)(k + 2) * 64 + e], a2);
            a3 = fma((double)xr[k + 3], (double)W[(size_t)(k + 3) * 64 + e], a3);
        }
        red[tid] = (a0 + a1) + (a2 + a3);
        __syncthreads();
        for (int st = 512; st >= 64; st >>= 1) {
            if (tid < st) red[tid] += red[tid + st];
            __syncthreads();
        }
        if (tid < 64) {
            const double z = red[tid] + (double)b[e];
            double v1 = z, v2 = -1e300;
            int i1 = e, i2 = 1 << 30;
#pragma unroll
            for (int mm = 1; mm < 64; mm <<= 1) {
                const double w1 = __shfl_xor(v1, mm, 64); const int j1 = __shfl_xor(i1, mm, 64);
                const double w2 = __shfl_xor(v2, mm, 64); const int j2 = __shfl_xor(i2, mm, 64);
                if (betterd(w1, j1, v1, i1)) {
                    double nv2; int ni2;
                    if (betterd(v1, i1, w2, j2)) { nv2 = v1; ni2 = i1; }
                    else                         { nv2 = w2; ni2 = j2; }
                    v1 = w1; i1 = j1; v2 = nv2; i2 = ni2;
                } else if (betterd(w1, j1, v2, i2)) { v2 = w1; i2 = j1; }
            }
            float sl = expf((float)(z - v1));
            float ssum = sl;
#pragma unroll
            for (int mm = 1; mm < 64; mm <<= 1) ssum += __shfl_xor(ssum, mm, 64);
            const float inv = 1.0f / ssum;
            if (e == 0) {
                const float s1 = fminf(fmaxf(inv, EPS_), 1.0f - EPS_);
                const float s2 = fminf(fmaxf(expf((float)(v2 - v1)) * inv, EPS_), 1.0f - EPS_);
                ts[row * 2 + 0] = s1;
                ts[row * 2 + 1] = s2;
                sel[row * 2 + 0] = i1;
                sel[row * 2 + 1] = i2;
            }
        }
        __syncthreads();
    }
}

// per-64-slot-chunk expert counts (transposed layout) + global histogram
__global__ void hist_chunks(const int* __restrict__ sel, int nchunks,
                            int* __restrict__ hist, int* __restrict__ cnt2)
{
    __shared__ int cnt[64];
    const int lane = threadIdx.x;   // 64
    const int c = blockIdx.x;
    cnt[lane] = 0;
    __syncthreads();
    const int ex = sel[c * 64 + lane];
    atomicAdd(&cnt[ex], 1);
    __syncthreads();
    cnt2[(size_t)lane * nchunks + c] = cnt[lane];
    if (cnt[lane]) atomicAdd(&hist[lane], cnt[lane]);
}

// per-batch rz sums (deterministic tree)
__global__ void rz_batch(const float* __restrict__ rzrow,
                         const int* __restrict__ bs_p, const int* __restrict__ sl_p,
                         double* __restrict__ bsum)
{
    __shared__ double red[256];
    const int nb = bs_p[0];
    const int seq = sl_p[0];
    for (int bb = blockIdx.x; bb < nb; bb += gridDim.x) {
        double s = 0.0;
        for (int i = threadIdx.x; i < seq; i += 256)
            s += (double)rzrow[(size_t)bb * seq + i];
        red[threadIdx.x] = s;
        __syncthreads();
        for (int st = 128; st > 0; st >>= 1) {
            if (threadIdx.x < st) red[threadIdx.x] += red[threadIdx.x + st];
            __syncthreads();
        }
        if (threadIdx.x == 0) bsum[bb] = red[0];
        __syncthreads();
    }
}

// expert starts (exclusive scan of hist) + out_cnt + rz finalize
__global__ void combine(const int* __restrict__ hist,
                        int* __restrict__ estart,
                        const double* __restrict__ bsum,
                        const int* __restrict__ bs_p,
                        float* __restrict__ out_cnt, float* __restrict__ out_rz)
{
    const int e = threadIdx.x;   // 64
    const int c0 = hist[e];
    int incl = c0;
#pragma unroll
    for (int mm = 1; mm < 64; mm <<= 1) {
        const int w = __shfl_up(incl, mm, 64);
        if (e >= mm) incl += w;
    }
    estart[e] = incl - c0;
    out_cnt[e] = (float)c0;
    if (e == 0) {
        const int nb = bs_p[0];
        double a = 0.0;
        for (int i = 0; i < nb; ++i) a += log(bsum[i]);
        out_rz[0] = (float)(a / nb);
    }
}

// parallel per-expert scan over chunks
__global__ __launch_bounds__(1024)
void chunk_scan(const int* __restrict__ cnt2, const int* __restrict__ estart,
                int nchunks, int* __restrict__ cbase)
{
    __shared__ int sc[1024];
    const int e = blockIdx.x;    // 64 blocks
    const int t = threadIdx.x;   // 1024
    const int v = (t < nchunks) ? cnt2[(size_t)e * nchunks + t] : 0;
    sc[t] = v;
    __syncthreads();
#pragma unroll
    for (int off = 1; off < 1024; off <<= 1) {
        const int add = (t >= off) ? sc[t - off] : 0;
        __syncthreads();
        sc[t] += add;
        __syncthreads();
    }
    if (t < nchunks)
        cbase[(size_t)t * 64 + e] = estart[e] + sc[t] - v;   // exclusive
}

// stable scatter per 64-slot chunk
__global__ void scatter(const int* __restrict__ sel, const float* __restrict__ ts,
                        const int* __restrict__ cbase,
                        float* __restrict__ out_sc, float* __restrict__ out_idx)
{
    __shared__ int shx[64];
    const int lane = threadIdx.x;   // 64
    const int c = blockIdx.x;
    const int idx = c * 64 + lane;
    const int ex = sel[idx];
    shx[lane] = ex;
    __syncthreads();
    int pre = 0;
#pragma unroll
    for (int j = 0; j < 64; ++j) pre += (int)((j < lane) && (shx[j] == ex));
    const int pos = cbase[c * 64 + ex] + pre;
    out_sc[pos]  = ts[idx];
    out_idx[pos] = (float)(idx >> 1);
}

extern "C" void kernel_launch(void* const* d_in, const int* in_sizes, int n_in,
                              void* d_out, int out_size, void* d_ws, size_t ws_size,
                              hipStream_t stream)
{
    const float* x = (const float*)d_in[0];
    const float* W = (const float*)d_in[1];
    const float* b = (const float*)d_in[2];
    const int* bs_p = (const int*)d_in[3];
    const int* sl_p = (const int*)d_in[4];

    const int E   = in_sizes[2];           // 64
    const int dim = in_sizes[1] / E;       // 2048
    const int N   = in_sizes[0] / dim;     // 16384
    const int total = N * 2;               // slots
    const int nchunks = total / 64;        // 512

    char* ws = (char*)d_ws;
    size_t off = 0;
    int*    hist     = (int*)(ws + off); off += 256;
    double* bsum     = (double*)(ws + off); off += 512;
    int*    nflags   = (int*)(ws + off); off += 256;
    int*    estart   = (int*)(ws + off); off += 256;
    float*  ts       = (float*)(ws + off); off += (size_t)total * 4;
    int*    sel      = (int*)(ws + off); off += (size_t)total * 4;
    int*    flaglist = (int*)(ws + off); off += (size_t)N * 4;
    float*  rzrow    = (float*)(ws + off); off += (size_t)N * 4;
    int*    cnt2     = (int*)(ws + off); off += (size_t)nchunks * 64 * 4;
    int*    cbase    = (int*)(ws + off); off += (size_t)nchunks * 64 * 4;
    unsigned short* wfg = (unsigned short*)(ws + off); off += (size_t)dim * 64 * 2 * 2;

    float* out_sc  = (float*)d_out;
    float* out_idx = out_sc + total;
    float* out_cnt = out_idx + total;
    float* out_rz  = out_cnt + E;

    hipMemsetAsync(ws, 0, 1280, stream);

    hipLaunchKernelGGL(wconv, dim3(dim * 64 / 256), dim3(256), 0, stream, W, wfg);
    hipLaunchKernelGGL(gemm_mfma, dim3(N / 16), dim3(256), 0, stream,
                       x, wfg, b, dim, N, ts, sel, rzrow, nflags, flaglist);
    hipLaunchKernelGGL(fixup, dim3(512), dim3(1024), 0, stream,
                       x, W, b, dim, nflags, flaglist, ts, sel);
    hipLaunchKernelGGL(hist_chunks, dim3(nchunks), dim3(64), 0, stream,
                       sel, nchunks, hist, cnt2);
    hipLaunchKernelGGL(rz_batch, dim3(64), dim3(256), 0, stream,
                       rzrow, bs_p, sl_p, bsum);
    hipLaunchKernelGGL(combine, dim3(1), dim3(64), 0, stream,
                       hist, estart, bsum, bs_p, out_cnt, out_rz);
    hipLaunchKernelGGL(chunk_scan, dim3(64), dim3(1024), 0, stream,
                       cnt2, estart, nchunks, cbase);
    hipLaunchKernelGGL(scatter, dim3(nchunks), dim3(64), 0, stream,
                       sel, ts, cbase, out_sc, out_idx);
}

// Round 12
// 102.338 us; speedup vs baseline: 1.8794x; 1.0005x over previous
//
#include <hip/hip_runtime.h>
#include <math.h>

#define EPS_ 1e-10f
#define MARGIN 4e-3f

typedef __attribute__((ext_vector_type(8))) short sh8;
typedef __attribute__((ext_vector_type(4))) float fx4;

__device__ __forceinline__ bool betterf(float v, int i, float w, int j) {
    return (v > w) || (v == w && i < j);
}
__device__ __forceinline__ bool betterd(double v, int i, double w, int j) {
    return (v > w) || (v == w && i < j);
}
__device__ __forceinline__ unsigned short f2bf(float f) {   // RNE
    unsigned u = __float_as_uint(f);
    u += 0x7fffu + ((u >> 16) & 1u);
    return (unsigned short)(u >> 16);
}
__device__ __forceinline__ float bf2f(unsigned short h) {
    return __uint_as_float(((unsigned)h) << 16);
}
__device__ __forceinline__ void cvt8(const float4 a, const float4 c, sh8& hi, sh8& lo) {
    const float v[8] = {a.x, a.y, a.z, a.w, c.x, c.y, c.z, c.w};
#pragma unroll
    for (int j = 0; j < 8; ++j) {
        const unsigned short h = f2bf(v[j]);
        hi[j] = (short)h;
        lo[j] = (short)f2bf(v[j] - bf2f(h));
    }
}

// ---------------------------------------------------------------------------
// One-time W conversion into B-fragment layout, bf16 hi/lo (layout verified).
// wf[((s*4+t)*2+hl)*512 + l*8 + j]; lane l=n+16*bq holds W[k=s*32+bq*8+j][e=t*16+n].
// ---------------------------------------------------------------------------
__global__ __launch_bounds__(256)
void wconv(const float* __restrict__ W, unsigned short* __restrict__ wf)
{
    const int gid = blockIdx.x * 256 + threadIdx.x;   // dim*64
    const int e = gid & 63, k = gid >> 6;
    const int s = k >> 5, kk = k & 31, bq = kk >> 3, j = kk & 7;
    const int t = e >> 4, n = e & 15;
    const int l = n + 16 * bq;
    const float w = W[(size_t)k * 64 + e];
    const unsigned short hi = f2bf(w);
    const unsigned short lo = f2bf(w - bf2f(hi));
    const size_t base = ((size_t)s * 4 + t) * 2;
    wf[(base + 0) * 512 + l * 8 + j] = hi;
    wf[(base + 1) * 512 + l * 8 + j] = lo;
}

// ---------------------------------------------------------------------------
// Fused MFMA router. Same shape as R11 (block = 4 waves x same 16 rows,
// in-block K-split, grid N/16 = 1024, 4 blocks/CU) PLUS full register
// double-buffering of BOTH x and W fragments one step ahead (two named
// register sets, 2-step unrolled loop, all indices static). Each step's
// 10 loads land under the previous step's cvt+MFMA across 4 waves/SIMD.
// ---------------------------------------------------------------------------
#define NKS 4
__global__ __launch_bounds__(256, 4)
void gemm_mfma(const float* __restrict__ x, const unsigned short* __restrict__ wfg,
               const float* __restrict__ b, int dim, int N,
               float* __restrict__ ts, int* __restrict__ sel,
               float* __restrict__ rzrow,
               int* __restrict__ nflags, int* __restrict__ flaglist)
{
    __shared__ float red[3][64][17];   // stride 17 -> conflict-free b32

    const int tid  = threadIdx.x;
    const int lane = tid & 63;
    const int wv   = tid >> 6;                // K-slice index
    const int r0   = blockIdx.x * 16;
    const int kslice = dim / NKS;             // 512
    const int k0   = wv * kslice;
    const int nstep = kslice / 32;            // 16 (even)

    const int m = lane & 15;
    const int q = lane >> 4;

    fx4 acc[4] = {};

    const float* xp = x + (size_t)(r0 + m) * dim + k0 + q * 8;
    const unsigned short* wbase = wfg + ((size_t)(k0 / 32) * 4096) + lane * 8;

    float4 xa0, xb0, xa1, xb1;
    sh8 bh0[4], bl0[4], bh1[4], bl1[4];

    // preload step 0 -> set0
    xa0 = *(const float4*)xp;
    xb0 = *(const float4*)(xp + 4);
#pragma unroll
    for (int t = 0; t < 4; ++t) {
        bh0[t] = __builtin_bit_cast(sh8, *(const int4*)(wbase + (t * 2 + 0) * 512));
        bl0[t] = __builtin_bit_cast(sh8, *(const int4*)(wbase + (t * 2 + 1) * 512));
    }

    for (int w = 0; w < nstep; w += 2) {
        // issue step w+1 loads into set1 (consumed next half-iteration)
        if (w + 1 < nstep) {
            xa1 = *(const float4*)(xp + (size_t)(w + 1) * 32);
            xb1 = *(const float4*)(xp + (size_t)(w + 1) * 32 + 4);
            const unsigned short* wk = wbase + (size_t)(w + 1) * 4096;
#pragma unroll
            for (int t = 0; t < 4; ++t) {
                bh1[t] = __builtin_bit_cast(sh8, *(const int4*)(wk + (t * 2 + 0) * 512));
                bl1[t] = __builtin_bit_cast(sh8, *(const int4*)(wk + (t * 2 + 1) * 512));
            }
        }
        // compute step w from set0
        {
            sh8 ahi, alo;
            cvt8(xa0, xb0, ahi, alo);
#pragma unroll
            for (int t = 0; t < 4; ++t)
                acc[t] = __builtin_amdgcn_mfma_f32_16x16x32_bf16(ahi, bh0[t], acc[t], 0, 0, 0);
#pragma unroll
            for (int t = 0; t < 4; ++t)
                acc[t] = __builtin_amdgcn_mfma_f32_16x16x32_bf16(ahi, bl0[t], acc[t], 0, 0, 0);
#pragma unroll
            for (int t = 0; t < 4; ++t)
                acc[t] = __builtin_amdgcn_mfma_f32_16x16x32_bf16(alo, bh0[t], acc[t], 0, 0, 0);
        }
        // issue step w+2 loads into set0
        if (w + 2 < nstep) {
            xa0 = *(const float4*)(xp + (size_t)(w + 2) * 32);
            xb0 = *(const float4*)(xp + (size_t)(w + 2) * 32 + 4);
            const unsigned short* wk = wbase + (size_t)(w + 2) * 4096;
#pragma unroll
            for (int t = 0; t < 4; ++t) {
                bh0[t] = __builtin_bit_cast(sh8, *(const int4*)(wk + (t * 2 + 0) * 512));
                bl0[t] = __builtin_bit_cast(sh8, *(const int4*)(wk + (t * 2 + 1) * 512));
            }
        }
        // compute step w+1 from set1
        if (w + 1 < nstep) {
            sh8 ahi, alo;
            cvt8(xa1, xb1, ahi, alo);
#pragma unroll
            for (int t = 0; t < 4; ++t)
                acc[t] = __builtin_amdgcn_mfma_f32_16x16x32_bf16(ahi, bh1[t], acc[t], 0, 0, 0);
#pragma unroll
            for (int t = 0; t < 4; ++t)
                acc[t] = __builtin_amdgcn_mfma_f32_16x16x32_bf16(ahi, bl1[t], acc[t], 0, 0, 0);
#pragma unroll
            for (int t = 0; t < 4; ++t)
                acc[t] = __builtin_amdgcn_mfma_f32_16x16x32_bf16(alo, bh1[t], acc[t], 0, 0, 0);
        }
    }

    // cross-wave K reduce (fixed order -> deterministic)
    if (wv > 0) {
#pragma unroll
        for (int t = 0; t < 4; ++t)
#pragma unroll
            for (int i = 0; i < 4; ++i)
                red[wv - 1][lane][t * 4 + i] = acc[t][i];
    }
    __syncthreads();
    if (wv != 0) return;

#pragma unroll
    for (int s = 0; s < 3; ++s)
#pragma unroll
        for (int t = 0; t < 4; ++t)
#pragma unroll
            for (int i = 0; i < 4; ++i)
                acc[t][i] += red[s][lane][t * 4 + i];

    // ---- fused epilogue (C layout: col=lane&15, row-in-16=(lane>>4)*4+i) ----
    const int n = lane & 15;
    const int g = lane >> 4;
    float bb[4];
#pragma unroll
    for (int t = 0; t < 4; ++t) bb[t] = b[t * 16 + n];

#pragma unroll
    for (int i = 0; i < 4; ++i) {
        const int row = r0 + g * 4 + i;
        float z[4];
#pragma unroll
        for (int t = 0; t < 4; ++t) z[t] = acc[t][i] + bb[t];

        float v1 = -3.4e38f, v2 = -3.4e38f;
        int i1 = 1 << 30, i2 = 1 << 30;
#pragma unroll
        for (int t = 0; t < 4; ++t) {
            const float v = z[t];
            const int e = t * 16 + n;
            if (v > v1)      { v2 = v1; i2 = i1; v1 = v; i1 = e; }
            else if (v > v2) { v2 = v;  i2 = e; }
        }
#pragma unroll
        for (int mm = 1; mm < 16; mm <<= 1) {
            const float w1 = __shfl_xor(v1, mm, 16); const int j1 = __shfl_xor(i1, mm, 16);
            const float w2 = __shfl_xor(v2, mm, 16); const int j2 = __shfl_xor(i2, mm, 16);
            if (betterf(w1, j1, v1, i1)) {
                float nv2; int ni2;
                if (betterf(v1, i1, w2, j2)) { nv2 = v1; ni2 = i1; }
                else                         { nv2 = w2; ni2 = j2; }
                v1 = w1; i1 = j1; v2 = nv2; i2 = ni2;
            } else if (betterf(w1, j1, v2, i2)) { v2 = w1; i2 = j1; }
        }

        float m3 = -3.4e38f;
#pragma unroll
        for (int t = 0; t < 4; ++t) {
            const int e = t * 16 + n;
            const bool skip = (e == i1) || (e == i2);
            m3 = skip ? m3 : fmaxf(m3, z[t]);
        }
#pragma unroll
        for (int mm = 1; mm < 16; mm <<= 1) m3 = fmaxf(m3, __shfl_xor(m3, mm, 16));

        float sloc[4], ssum = 0.0f;
#pragma unroll
        for (int t = 0; t < 4; ++t) { sloc[t] = expf(z[t] - v1); ssum += sloc[t]; }
#pragma unroll
        for (int mm = 1; mm < 16; mm <<= 1) ssum += __shfl_xor(ssum, mm, 16);
        const float inv = 1.0f / ssum;
        float srz = 0.0f;
#pragma unroll
        for (int t = 0; t < 4; ++t) {
            float sc = fminf(fmaxf(sloc[t] * inv, EPS_), 1.0f - EPS_);
            srz += sc / (1.0f - sc);
        }
#pragma unroll
        for (int mm = 1; mm < 16; mm <<= 1) srz += __shfl_xor(srz, mm, 16);

        if (n == 0) {
            const float s1 = fminf(fmaxf(inv, EPS_), 1.0f - EPS_);
            const float s2 = fminf(fmaxf(expf(v2 - v1) * inv, EPS_), 1.0f - EPS_);
            ts[row * 2 + 0] = s1;
            ts[row * 2 + 1] = s2;
            sel[row * 2 + 0] = i1;
            sel[row * 2 + 1] = i2;
            rzrow[row] = srz;
            if ((v1 - v2) < MARGIN || (v2 - m3) < MARGIN) {
                const int slot = atomicAdd(nflags, 1);
                flaglist[slot] = row;
            }
        }
    }
}

// ---------------------------------------------------------------------------
// fp64 recompute of flagged near-tie rows. 1024 thr = 64 e x 16 K-slices.
// ---------------------------------------------------------------------------
__global__ __launch_bounds__(1024)
void fixup(const float* __restrict__ x, const float* __restrict__ W,
           const float* __restrict__ b, int dim,
           const int* __restrict__ nflags, const int* __restrict__ flaglist,
           float* __restrict__ ts, int* __restrict__ sel)
{
    __shared__ double red[1024];
    const int tid = threadIdx.x;
    const int e = tid & 63;
    const int q = tid >> 6;              // 0..15
    const int nf = *nflags;
    const int slice = dim >> 4;          // 128

    for (int f = blockIdx.x; f < nf; f += gridDim.x) {
        const int row = flaglist[f];
        const float* xr = x + (size_t)row * dim;
        const int k0 = q * slice;
        double a0 = 0.0, a1 = 0.0, a2 = 0.0, a3 = 0.0;
        for (int k = k0; k < k0 + slice; k += 4) {
            a0 = fma((double)xr[k + 0], (double)W[(size_t)(k + 0) * 64 + e], a0);
            a1 = fma((double)xr[k + 1], (double)W[(size_t)(k + 1) * 64 + e], a1);
            a2 = fma((double)xr[k + 2], (double)W[(size_t)(k + 2) * 64 + e], a2);
            a3 = fma((double)xr[k + 3], (double)W[(size_t)(k + 3) * 64 + e], a3);
        }
        red[tid] = (a0 + a1) + (a2 + a3);
        __syncthreads();
        for (int st = 512; st >= 64; st >>= 1) {
            if (tid < st) red[tid] += red[tid + st];
            __syncthreads();
        }
        if (tid < 64) {
            const double z = red[tid] + (double)b[e];
            double v1 = z, v2 = -1e300;
            int i1 = e, i2 = 1 << 30;
#pragma unroll
            for (int mm = 1; mm < 64; mm <<= 1) {
                const double w1 = __shfl_xor(v1, mm, 64); const int j1 = __shfl_xor(i1, mm, 64);
                const double w2 = __shfl_xor(v2, mm, 64); const int j2 = __shfl_xor(i2, mm, 64);
                if (betterd(w1, j1, v1, i1)) {
                    double nv2; int ni2;
                    if (betterd(v1, i1, w2, j2)) { nv2 = v1; ni2 = i1; }
                    else                         { nv2 = w2; ni2 = j2; }
                    v1 = w1; i1 = j1; v2 = nv2; i2 = ni2;
                } else if (betterd(w1, j1, v2, i2)) { v2 = w1; i2 = j1; }
            }
            float sl = expf((float)(z - v1));
            float ssum = sl;
#pragma unroll
            for (int mm = 1; mm < 64; mm <<= 1) ssum += __shfl_xor(ssum, mm, 64);
            const float inv = 1.0f / ssum;
            if (e == 0) {
                const float s1 = fminf(fmaxf(inv, EPS_), 1.0f - EPS_);
                const float s2 = fminf(fmaxf(expf((float)(v2 - v1)) * inv, EPS_), 1.0f - EPS_);
                ts[row * 2 + 0] = s1;
                ts[row * 2 + 1] = s2;
                sel[row * 2 + 0] = i1;
                sel[row * 2 + 1] = i2;
            }
        }
        __syncthreads();
    }
}

// per-64-slot-chunk expert counts (transposed layout) + global histogram
__global__ void hist_chunks(const int* __restrict__ sel, int nchunks,
                            int* __restrict__ hist, int* __restrict__ cnt2)
{
    __shared__ int cnt[64];
    const int lane = threadIdx.x;   // 64
    const int c = blockIdx.x;
    cnt[lane] = 0;
    __syncthreads();
    const int ex = sel[c * 64 + lane];
    atomicAdd(&cnt[ex], 1);
    __syncthreads();
    cnt2[(size_t)lane * nchunks + c] = cnt[lane];
    if (cnt[lane]) atomicAdd(&hist[lane], cnt[lane]);
}

// per-batch rz sums (deterministic tree)
__global__ void rz_batch(const float* __restrict__ rzrow,
                         const int* __restrict__ bs_p, const int* __restrict__ sl_p,
                         double* __restrict__ bsum)
{
    __shared__ double red[256];
    const int nb = bs_p[0];
    const int seq = sl_p[0];
    for (int bb = blockIdx.x; bb < nb; bb += gridDim.x) {
        double s = 0.0;
        for (int i = threadIdx.x; i < seq; i += 256)
            s += (double)rzrow[(size_t)bb * seq + i];
        red[threadIdx.x] = s;
        __syncthreads();
        for (int st = 128; st > 0; st >>= 1) {
            if (threadIdx.x < st) red[threadIdx.x] += red[threadIdx.x + st];
            __syncthreads();
        }
        if (threadIdx.x == 0) bsum[bb] = red[0];
        __syncthreads();
    }
}

// expert starts (exclusive scan of hist) + out_cnt + rz finalize
__global__ void combine(const int* __restrict__ hist,
                        int* __restrict__ estart,
                        const double* __restrict__ bsum,
                        const int* __restrict__ bs_p,
                        float* __restrict__ out_cnt, float* __restrict__ out_rz)
{
    const int e = threadIdx.x;   // 64
    const int c0 = hist[e];
    int incl = c0;
#pragma unroll
    for (int mm = 1; mm < 64; mm <<= 1) {
        const int w = __shfl_up(incl, mm, 64);
        if (e >= mm) incl += w;
    }
    estart[e] = incl - c0;
    out_cnt[e] = (float)c0;
    if (e == 0) {
        const int nb = bs_p[0];
        double a = 0.0;
        for (int i = 0; i < nb; ++i) a += log(bsum[i]);
        out_rz[0] = (float)(a / nb);
    }
}

// parallel per-expert scan over chunks
__global__ __launch_bounds__(1024)
void chunk_scan(const int* __restrict__ cnt2, const int* __restrict__ estart,
                int nchunks, int* __restrict__ cbase)
{
    __shared__ int sc[1024];
    const int e = blockIdx.x;    // 64 blocks
    const int t = threadIdx.x;   // 1024
    const int v = (t < nchunks) ? cnt2[(size_t)e * nchunks + t] : 0;
    sc[t] = v;
    __syncthreads();
#pragma unroll
    for (int off = 1; off < 1024; off <<= 1) {
        const int add = (t >= off) ? sc[t - off] : 0;
        __syncthreads();
        sc[t] += add;
        __syncthreads();
    }
    if (t < nchunks)
        cbase[(size_t)t * 64 + e] = estart[e] + sc[t] - v;   // exclusive
}

// stable scatter per 64-slot chunk
__global__ void scatter(const int* __restrict__ sel, const float* __restrict__ ts,
                        const int* __restrict__ cbase,
                        float* __restrict__ out_sc, float* __restrict__ out_idx)
{
    __shared__ int shx[64];
    const int lane = threadIdx.x;   // 64
    const int c = blockIdx.x;
    const int idx = c * 64 + lane;
    const int ex = sel[idx];
    shx[lane] = ex;
    __syncthreads();
    int pre = 0;
#pragma unroll
    for (int j = 0; j < 64; ++j) pre += (int)((j < lane) && (shx[j] == ex));
    const int pos = cbase[c * 64 + ex] + pre;
    out_sc[pos]  = ts[idx];
    out_idx[pos] = (float)(idx >> 1);
}

extern "C" void kernel_launch(void* const* d_in, const int* in_sizes, int n_in,
                              void* d_out, int out_size, void* d_ws, size_t ws_size,
                              hipStream_t stream)
{
    const float* x = (const float*)d_in[0];
    const float* W = (const float*)d_in[1];
    const float* b = (const float*)d_in[2];
    const int* bs_p = (const int*)d_in[3];
    const int* sl_p = (const int*)d_in[4];

    const int E   = in_sizes[2];           // 64
    const int dim = in_sizes[1] / E;       // 2048
    const int N   = in_sizes[0] / dim;     // 16384
    const int total = N * 2;               // slots
    const int nchunks = total / 64;        // 512

    char* ws = (char*)d_ws;
    size_t off = 0;
    int*    hist     = (int*)(ws + off); off += 256;
    double* bsum     = (double*)(ws + off); off += 512;
    int*    nflags   = (int*)(ws + off); off += 256;
    int*    estart   = (int*)(ws + off); off += 256;
    float*  ts       = (float*)(ws + off); off += (size_t)total * 4;
    int*    sel      = (int*)(ws + off); off += (size_t)total * 4;
    int*    flaglist = (int*)(ws + off); off += (size_t)N * 4;
    float*  rzrow    = (float*)(ws + off); off += (size_t)N * 4;
    int*    cnt2     = (int*)(ws + off); off += (size_t)nchunks * 64 * 4;
    int*    cbase    = (int*)(ws + off); off += (size_t)nchunks * 64 * 4;
    unsigned short* wfg = (unsigned short*)(ws + off); off += (size_t)dim * 64 * 2 * 2;

    float* out_sc  = (float*)d_out;
    float* out_idx = out_sc + total;
    float* out_cnt = out_idx + total;
    float* out_rz  = out_cnt + E;

    hipMemsetAsync(ws, 0, 1280, stream);

    hipLaunchKernelGGL(wconv, dim3(dim * 64 / 256), dim3(256), 0, stream, W, wfg);
    hipLaunchKernelGGL(gemm_mfma, dim3(N / 16), dim3(256), 0, stream,
                       x, wfg, b, dim, N, ts, sel, rzrow, nflags, flaglist);
    hipLaunchKernelGGL(fixup, dim3(512), dim3(1024), 0, stream,
                       x, W, b, dim, nflags, flaglist, ts, sel);
    hipLaunchKernelGGL(hist_chunks, dim3(nchunks), dim3(64), 0, stream,
                       sel, nchunks, hist, cnt2);
    hipLaunchKernelGGL(rz_batch, dim3(64), dim3(256), 0, stream,
                       rzrow, bs_p, sl_p, bsum);
    hipLaunchKernelGGL(combine, dim3(1), dim3(64), 0, stream,
                       hist, estart, bsum, bs_p, out_cnt, out_rz);
    hipLaunchKernelGGL(chunk_scan, dim3(64), dim3(1024), 0, stream,
                       cnt2, estart, nchunks, cbase);
    hipLaunchKernelGGL(scatter, dim3(nchunks), dim3(64), 0, stream,
                       sel, ts, cbase, out_sc, out_idx);
}

// Round 13
// 99.663 us; speedup vs baseline: 1.9299x; 1.0268x over previous
//
#include <hip/hip_runtime.h>
#include <math.h>

#define EPS_ 1e-10f
#define MARGIN 4e-3f

typedef __attribute__((ext_vector_type(8))) short sh8;
typedef __attribute__((ext_vector_type(4))) float fx4;

__device__ __forceinline__ bool betterf(float v, int i, float w, int j) {
    return (v > w) || (v == w && i < j);
}
__device__ __forceinline__ bool betterd(double v, int i, double w, int j) {
    return (v > w) || (v == w && i < j);
}
__device__ __forceinline__ unsigned short f2bf(float f) {   // RNE
    unsigned u = __float_as_uint(f);
    u += 0x7fffu + ((u >> 16) & 1u);
    return (unsigned short)(u >> 16);
}
__device__ __forceinline__ float bf2f(unsigned short h) {
    return __uint_as_float(((unsigned)h) << 16);
}
__device__ __forceinline__ void cvt8(const float4 a, const float4 c, sh8& hi, sh8& lo) {
    const float v[8] = {a.x, a.y, a.z, a.w, c.x, c.y, c.z, c.w};
#pragma unroll
    for (int j = 0; j < 8; ++j) {
        const unsigned short h = f2bf(v[j]);
        hi[j] = (short)h;
        lo[j] = (short)f2bf(v[j] - bf2f(h));
    }
}

// ---------------------------------------------------------------------------
// One-time W conversion into B-fragment layout, bf16 hi/lo (layout verified).
// wf[((s*4+t)*2+hl)*512 + l*8 + j]; lane l=n+16*bq holds W[k=s*32+bq*8+j][e=t*16+n].
// ---------------------------------------------------------------------------
__global__ __launch_bounds__(256)
void wconv(const float* __restrict__ W, unsigned short* __restrict__ wf)
{
    const int gid = blockIdx.x * 256 + threadIdx.x;   // dim*64
    const int e = gid & 63, k = gid >> 6;
    const int s = k >> 5, kk = k & 31, bq = kk >> 3, j = kk & 7;
    const int t = e >> 4, n = e & 15;
    const int l = n + 16 * bq;
    const float w = W[(size_t)k * 64 + e];
    const unsigned short hi = f2bf(w);
    const unsigned short lo = f2bf(w - bf2f(hi));
    const size_t base = ((size_t)s * 4 + t) * 2;
    wf[(base + 0) * 512 + l * 8 + j] = hi;
    wf[(base + 1) * 512 + l * 8 + j] = lo;
}

// ---------------------------------------------------------------------------
// Fused MFMA router, W-amortized: block = 512 thr = 8 waves; each wave
// covers ALL 64 rows (4 row-tiles) x 64 experts for its K-eighth (8 steps
// of K=32). One W-fragment read feeds 4 row-tiles (48 MFMAs) -> W traffic
// drops 512MB -> 128MB and W VMEM instr count drops 4x. W prefetched one
// step ahead (named sets). No barriers in K loop. Cross-wave K reduce via
// LDS tree, then 64-lane-butterfly epilogue, 8 rows per wave.
// Grid = N/64 = 256 blocks (1 block/CU, 2 waves/SIMD).
// ---------------------------------------------------------------------------
__global__ __launch_bounds__(512, 2)
void gemm_mfma(const float* __restrict__ x, const unsigned short* __restrict__ wfg,
               const float* __restrict__ b, int dim, int N,
               float* __restrict__ ts, int* __restrict__ sel,
               float* __restrict__ rzrow,
               int* __restrict__ nflags, int* __restrict__ flaglist)
{
    __shared__ float slots[4][64][65];   // reduce tree + final z; 66.6KB

    const int tid  = threadIdx.x;
    const int lane = tid & 63;
    const int wv   = tid >> 6;                 // 0..7 = K-slice
    const int r0   = blockIdx.x * 64;
    const int kslice = dim >> 3;               // 256
    const int k0   = wv * kslice;
    const int nstep = kslice >> 5;             // 8 (even)

    const int m = lane & 15;                   // row within tile
    const int q = lane >> 4;                   // k-quad / row-group

    fx4 acc[4][4];
#pragma unroll
    for (int t = 0; t < 4; ++t)
#pragma unroll
        for (int te = 0; te < 4; ++te)
            acc[t][te] = (fx4){0.f, 0.f, 0.f, 0.f};

    const float* xp0 = x + (size_t)(r0 +  0 + m) * dim + k0 + q * 8;
    const float* xp1 = x + (size_t)(r0 + 16 + m) * dim + k0 + q * 8;
    const float* xp2 = x + (size_t)(r0 + 32 + m) * dim + k0 + q * 8;
    const float* xp3 = x + (size_t)(r0 + 48 + m) * dim + k0 + q * 8;
    const unsigned short* wbase = wfg + (size_t)(k0 >> 5) * 4096 + lane * 8;

    sh8 w0h[4], w0l[4], w1h[4], w1l[4];
#pragma unroll
    for (int te = 0; te < 4; ++te) {
        w0h[te] = __builtin_bit_cast(sh8, *(const int4*)(wbase + (te * 2 + 0) * 512));
        w0l[te] = __builtin_bit_cast(sh8, *(const int4*)(wbase + (te * 2 + 1) * 512));
    }

    for (int w = 0; w < nstep; w += 2) {
        // prefetch W for step w+1
        {
            const unsigned short* wk = wbase + (size_t)(w + 1) * 4096;
#pragma unroll
            for (int te = 0; te < 4; ++te) {
                w1h[te] = __builtin_bit_cast(sh8, *(const int4*)(wk + (te * 2 + 0) * 512));
                w1l[te] = __builtin_bit_cast(sh8, *(const int4*)(wk + (te * 2 + 1) * 512));
            }
        }
        // ---- step w: x loads (8 float4, issued together), cvt+MFMA per tile ----
        {
            float4 xa0 = *(const float4*)(xp0 + (size_t)w * 32);
            float4 xb0 = *(const float4*)(xp0 + (size_t)w * 32 + 4);
            float4 xa1 = *(const float4*)(xp1 + (size_t)w * 32);
            float4 xb1 = *(const float4*)(xp1 + (size_t)w * 32 + 4);
            float4 xa2 = *(const float4*)(xp2 + (size_t)w * 32);
            float4 xb2 = *(const float4*)(xp2 + (size_t)w * 32 + 4);
            float4 xa3 = *(const float4*)(xp3 + (size_t)w * 32);
            float4 xb3 = *(const float4*)(xp3 + (size_t)w * 32 + 4);
            sh8 ah, al;
            cvt8(xa0, xb0, ah, al);
#pragma unroll
            for (int te = 0; te < 4; ++te) {
                acc[0][te] = __builtin_amdgcn_mfma_f32_16x16x32_bf16(ah, w0h[te], acc[0][te], 0, 0, 0);
                acc[0][te] = __builtin_amdgcn_mfma_f32_16x16x32_bf16(ah, w0l[te], acc[0][te], 0, 0, 0);
                acc[0][te] = __builtin_amdgcn_mfma_f32_16x16x32_bf16(al, w0h[te], acc[0][te], 0, 0, 0);
            }
            cvt8(xa1, xb1, ah, al);
#pragma unroll
            for (int te = 0; te < 4; ++te) {
                acc[1][te] = __builtin_amdgcn_mfma_f32_16x16x32_bf16(ah, w0h[te], acc[1][te], 0, 0, 0);
                acc[1][te] = __builtin_amdgcn_mfma_f32_16x16x32_bf16(ah, w0l[te], acc[1][te], 0, 0, 0);
                acc[1][te] = __builtin_amdgcn_mfma_f32_16x16x32_bf16(al, w0h[te], acc[1][te], 0, 0, 0);
            }
            cvt8(xa2, xb2, ah, al);
#pragma unroll
            for (int te = 0; te < 4; ++te) {
                acc[2][te] = __builtin_amdgcn_mfma_f32_16x16x32_bf16(ah, w0h[te], acc[2][te], 0, 0, 0);
                acc[2][te] = __builtin_amdgcn_mfma_f32_16x16x32_bf16(ah, w0l[te], acc[2][te], 0, 0, 0);
                acc[2][te] = __builtin_amdgcn_mfma_f32_16x16x32_bf16(al, w0h[te], acc[2][te], 0, 0, 0);
            }
            cvt8(xa3, xb3, ah, al);
#pragma unroll
            for (int te = 0; te < 4; ++te) {
                acc[3][te] = __builtin_amdgcn_mfma_f32_16x16x32_bf16(ah, w0h[te], acc[3][te], 0, 0, 0);
                acc[3][te] = __builtin_amdgcn_mfma_f32_16x16x32_bf16(ah, w0l[te], acc[3][te], 0, 0, 0);
                acc[3][te] = __builtin_amdgcn_mfma_f32_16x16x32_bf16(al, w0h[te], acc[3][te], 0, 0, 0);
            }
        }
        // prefetch W for step w+2
        if (w + 2 < nstep) {
            const unsigned short* wk = wbase + (size_t)(w + 2) * 4096;
#pragma unroll
            for (int te = 0; te < 4; ++te) {
                w0h[te] = __builtin_bit_cast(sh8, *(const int4*)(wk + (te * 2 + 0) * 512));
                w0l[te] = __builtin_bit_cast(sh8, *(const int4*)(wk + (te * 2 + 1) * 512));
            }
        }
        // ---- step w+1: compute with W set 1 ----
        {
            const int w1 = w + 1;
            float4 xa0 = *(const float4*)(xp0 + (size_t)w1 * 32);
            float4 xb0 = *(const float4*)(xp0 + (size_t)w1 * 32 + 4);
            float4 xa1 = *(const float4*)(xp1 + (size_t)w1 * 32);
            float4 xb1 = *(const float4*)(xp1 + (size_t)w1 * 32 + 4);
            float4 xa2 = *(const float4*)(xp2 + (size_t)w1 * 32);
            float4 xb2 = *(const float4*)(xp2 + (size_t)w1 * 32 + 4);
            float4 xa3 = *(const float4*)(xp3 + (size_t)w1 * 32);
            float4 xb3 = *(const float4*)(xp3 + (size_t)w1 * 32 + 4);
            sh8 ah, al;
            cvt8(xa0, xb0, ah, al);
#pragma unroll
            for (int te = 0; te < 4; ++te) {
                acc[0][te] = __builtin_amdgcn_mfma_f32_16x16x32_bf16(ah, w1h[te], acc[0][te], 0, 0, 0);
                acc[0][te] = __builtin_amdgcn_mfma_f32_16x16x32_bf16(ah, w1l[te], acc[0][te], 0, 0, 0);
                acc[0][te] = __builtin_amdgcn_mfma_f32_16x16x32_bf16(al, w1h[te], acc[0][te], 0, 0, 0);
            }
            cvt8(xa1, xb1, ah, al);
#pragma unroll
            for (int te = 0; te < 4; ++te) {
                acc[1][te] = __builtin_amdgcn_mfma_f32_16x16x32_bf16(ah, w1h[te], acc[1][te], 0, 0, 0);
                acc[1][te] = __builtin_amdgcn_mfma_f32_16x16x32_bf16(ah, w1l[te], acc[1][te], 0, 0, 0);
                acc[1][te] = __builtin_amdgcn_mfma_f32_16x16x32_bf16(al, w1h[te], acc[1][te], 0, 0, 0);
            }
            cvt8(xa2, xb2, ah, al);
#pragma unroll
            for (int te = 0; te < 4; ++te) {
                acc[2][te] = __builtin_amdgcn_mfma_f32_16x16x32_bf16(ah, w1h[te], acc[2][te], 0, 0, 0);
                acc[2][te] = __builtin_amdgcn_mfma_f32_16x16x32_bf16(ah, w1l[te], acc[2][te], 0, 0, 0);
                acc[2][te] = __builtin_amdgcn_mfma_f32_16x16x32_bf16(al, w1h[te], acc[2][te], 0, 0, 0);
            }
            cvt8(xa3, xb3, ah, al);
#pragma unroll
            for (int te = 0; te < 4; ++te) {
                acc[3][te] = __builtin_amdgcn_mfma_f32_16x16x32_bf16(ah, w1h[te], acc[3][te], 0, 0, 0);
                acc[3][te] = __builtin_amdgcn_mfma_f32_16x16x32_bf16(ah, w1l[te], acc[3][te], 0, 0, 0);
                acc[3][te] = __builtin_amdgcn_mfma_f32_16x16x32_bf16(al, w1h[te], acc[3][te], 0, 0, 0);
            }
        }
    }

    // ---- cross-wave K reduce: pairwise LDS tree, fixed order ----
    const int n = lane & 15;
#pragma unroll
    for (int s = 4; s >= 1; s >>= 1) {
        if (wv >= s && wv < 2 * s) {
            float (*slot)[65] = slots[wv - s];
#pragma unroll
            for (int t = 0; t < 4; ++t)
#pragma unroll
                for (int te = 0; te < 4; ++te)
#pragma unroll
                    for (int i = 0; i < 4; ++i)
                        slot[t * 16 + q * 4 + i][te * 16 + n] = acc[t][te][i];
        }
        __syncthreads();
        if (wv < s) {
            float (*slot)[65] = slots[wv];
#pragma unroll
            for (int t = 0; t < 4; ++t)
#pragma unroll
                for (int te = 0; te < 4; ++te)
#pragma unroll
                    for (int i = 0; i < 4; ++i)
                        acc[t][te][i] += slot[t * 16 + q * 4 + i][te * 16 + n];
        }
        __syncthreads();
    }

    // wave 0 publishes final z
    if (wv == 0) {
#pragma unroll
        for (int t = 0; t < 4; ++t)
#pragma unroll
            for (int te = 0; te < 4; ++te)
#pragma unroll
                for (int i = 0; i < 4; ++i)
                    slots[0][t * 16 + q * 4 + i][te * 16 + n] = acc[t][te][i];
    }
    __syncthreads();

    // ---- epilogue: wave wv handles rows [wv*8, wv*8+8), lane = expert ----
    const int e = lane;
    const float be = b[e];
    for (int rr = 0; rr < 8; ++rr) {
        const int lrow = wv * 8 + rr;
        const int row = r0 + lrow;
        const float z = slots[0][lrow][e] + be;

        float v1 = z, v2 = -3.4e38f;
        int i1 = e, i2 = 1 << 30;
#pragma unroll
        for (int mm = 1; mm < 64; mm <<= 1) {
            const float wva = __shfl_xor(v1, mm, 64); const int j1 = __shfl_xor(i1, mm, 64);
            const float wvb = __shfl_xor(v2, mm, 64); const int j2 = __shfl_xor(i2, mm, 64);
            if (betterf(wva, j1, v1, i1)) {
                float nv2; int ni2;
                if (betterf(v1, i1, wvb, j2)) { nv2 = v1; ni2 = i1; }
                else                          { nv2 = wvb; ni2 = j2; }
                v1 = wva; i1 = j1; v2 = nv2; i2 = ni2;
            } else if (betterf(wva, j1, v2, i2)) { v2 = wva; i2 = j1; }
        }

        float m3 = (e == i1 || e == i2) ? -3.4e38f : z;
#pragma unroll
        for (int mm = 1; mm < 64; mm <<= 1) m3 = fmaxf(m3, __shfl_xor(m3, mm, 64));

        const float ex = expf(z - v1);
        float ssum = ex;
#pragma unroll
        for (int mm = 1; mm < 64; mm <<= 1) ssum += __shfl_xor(ssum, mm, 64);
        const float inv = 1.0f / ssum;

        float sc = fminf(fmaxf(ex * inv, EPS_), 1.0f - EPS_);
        float srz = sc / (1.0f - sc);
#pragma unroll
        for (int mm = 1; mm < 64; mm <<= 1) srz += __shfl_xor(srz, mm, 64);

        if (e == 0) {
            const float s1 = fminf(fmaxf(inv, EPS_), 1.0f - EPS_);
            const float s2 = fminf(fmaxf(expf(v2 - v1) * inv, EPS_), 1.0f - EPS_);
            ts[row * 2 + 0] = s1;
            ts[row * 2 + 1] = s2;
            sel[row * 2 + 0] = i1;
            sel[row * 2 + 1] = i2;
            rzrow[row] = srz;
            if ((v1 - v2) < MARGIN || (v2 - m3) < MARGIN) {
                const int slot2 = atomicAdd(nflags, 1);
                flaglist[slot2] = row;
            }
        }
    }
}

// ---------------------------------------------------------------------------
// fp64 recompute of flagged near-tie rows. 1024 thr = 64 e x 16 K-slices.
// ---------------------------------------------------------------------------
__global__ __launch_bounds__(1024)
void fixup(const float* __restrict__ x, const float* __restrict__ W,
           const float* __restrict__ b, int dim,
           const int* __restrict__ nflags, const int* __restrict__ flaglist,
           float* __restrict__ ts, int* __restrict__ sel)
{
    __shared__ double red[1024];
    const int tid = threadIdx.x;
    const int e = tid & 63;
    const int q = tid >> 6;              // 0..15
    const int nf = *nflags;
    const int slice = dim >> 4;          // 128

    for (int f = blockIdx.x; f < nf; f += gridDim.x) {
        const int row = flaglist[f];
        const float* xr = x + (size_t)row * dim;
        const int k0 = q * slice;
        double a0 = 0.0, a1 = 0.0, a2 = 0.0, a3 = 0.0;
        for (int k = k0; k < k0 + slice; k += 4) {
            a0 = fma((double)xr[k + 0], (double)W[(size_t)(k + 0) * 64 + e], a0);
            a1 = fma((double)xr[k + 1], (double)W[(size_t)(k + 1) * 64 + e], a1);
            a2 = fma((double)xr[k + 2], (double)W[(size_t)(k + 2) * 64 + e], a2);
            a3 = fma((double)xr[k + 3], (double)W[(size_t)(k + 3) * 64 + e], a3);
        }
        red[tid] = (a0 + a1) + (a2 + a3);
        __syncthreads();
        for (int st = 512; st >= 64; st >>= 1) {
            if (tid < st) red[tid] += red[tid + st];
            __syncthreads();
        }
        if (tid < 64) {
            const double z = red[tid] + (double)b[e];
            double v1 = z, v2 = -1e300;
            int i1 = e, i2 = 1 << 30;
#pragma unroll
            for (int mm = 1; mm < 64; mm <<= 1) {
                const double w1 = __shfl_xor(v1, mm, 64); const int j1 = __shfl_xor(i1, mm, 64);
                const double w2 = __shfl_xor(v2, mm, 64); const int j2 = __shfl_xor(i2, mm, 64);
                if (betterd(w1, j1, v1, i1)) {
                    double nv2; int ni2;
                    if (betterd(v1, i1, w2, j2)) { nv2 = v1; ni2 = i1; }
                    else                         { nv2 = w2; ni2 = j2; }
                    v1 = w1; i1 = j1; v2 = nv2; i2 = ni2;
                } else if (betterd(w1, j1, v2, i2)) { v2 = w1; i2 = j1; }
            }
            float sl = expf((float)(z - v1));
            float ssum = sl;
#pragma unroll
            for (int mm = 1; mm < 64; mm <<= 1) ssum += __shfl_xor(ssum, mm, 64);
            const float inv = 1.0f / ssum;
            if (e == 0) {
                const float s1 = fminf(fmaxf(inv, EPS_), 1.0f - EPS_);
                const float s2 = fminf(fmaxf(expf((float)(v2 - v1)) * inv, EPS_), 1.0f - EPS_);
                ts[row * 2 + 0] = s1;
                ts[row * 2 + 1] = s2;
                sel[row * 2 + 0] = i1;
                sel[row * 2 + 1] = i2;
            }
        }
        __syncthreads();
    }
}

// per-64-slot-chunk expert counts (transposed layout) + global histogram
__global__ void hist_chunks(const int* __restrict__ sel, int nchunks,
                            int* __restrict__ hist, int* __restrict__ cnt2)
{
    __shared__ int cnt[64];
    const int lane = threadIdx.x;   // 64
    const int c = blockIdx.x;
    cnt[lane] = 0;
    __syncthreads();
    const int ex = sel[c * 64 + lane];
    atomicAdd(&cnt[ex], 1);
    __syncthreads();
    cnt2[(size_t)lane * nchunks + c] = cnt[lane];
    if (cnt[lane]) atomicAdd(&hist[lane], cnt[lane]);
}

// per-batch rz sums (deterministic tree)
__global__ void rz_batch(const float* __restrict__ rzrow,
                         const int* __restrict__ bs_p, const int* __restrict__ sl_p,
                         double* __restrict__ bsum)
{
    __shared__ double red[256];
    const int nb = bs_p[0];
    const int seq = sl_p[0];
    for (int bb = blockIdx.x; bb < nb; bb += gridDim.x) {
        double s = 0.0;
        for (int i = threadIdx.x; i < seq; i += 256)
            s += (double)rzrow[(size_t)bb * seq + i];
        red[threadIdx.x] = s;
        __syncthreads();
        for (int st = 128; st > 0; st >>= 1) {
            if (threadIdx.x < st) red[threadIdx.x] += red[threadIdx.x + st];
            __syncthreads();
        }
        if (threadIdx.x == 0) bsum[bb] = red[0];
        __syncthreads();
    }
}

// expert starts (exclusive scan of hist) + out_cnt + rz finalize
__global__ void combine(const int* __restrict__ hist,
                        int* __restrict__ estart,
                        const double* __restrict__ bsum,
                        const int* __restrict__ bs_p,
                        float* __restrict__ out_cnt, float* __restrict__ out_rz)
{
    const int e = threadIdx.x;   // 64
    const int c0 = hist[e];
    int incl = c0;
#pragma unroll
    for (int mm = 1; mm < 64; mm <<= 1) {
        const int w = __shfl_up(incl, mm, 64);
        if (e >= mm) incl += w;
    }
    estart[e] = incl - c0;
    out_cnt[e] = (float)c0;
    if (e == 0) {
        const int nb = bs_p[0];
        double a = 0.0;
        for (int i = 0; i < nb; ++i) a += log(bsum[i]);
        out_rz[0] = (float)(a / nb);
    }
}

// parallel per-expert scan over chunks
__global__ __launch_bounds__(1024)
void chunk_scan(const int* __restrict__ cnt2, const int* __restrict__ estart,
                int nchunks, int* __restrict__ cbase)
{
    __shared__ int sc[1024];
    const int e = blockIdx.x;    // 64 blocks
    const int t = threadIdx.x;   // 1024
    const int v = (t < nchunks) ? cnt2[(size_t)e * nchunks + t] : 0;
    sc[t] = v;
    __syncthreads();
#pragma unroll
    for (int off = 1; off < 1024; off <<= 1) {
        const int add = (t >= off) ? sc[t - off] : 0;
        __syncthreads();
        sc[t] += add;
        __syncthreads();
    }
    if (t < nchunks)
        cbase[(size_t)t * 64 + e] = estart[e] + sc[t] - v;   // exclusive
}

// stable scatter per 64-slot chunk
__global__ void scatter(const int* __restrict__ sel, const float* __restrict__ ts,
                        const int* __restrict__ cbase,
                        float* __restrict__ out_sc, float* __restrict__ out_idx)
{
    __shared__ int shx[64];
    const int lane = threadIdx.x;   // 64
    const int c = blockIdx.x;
    const int idx = c * 64 + lane;
    const int ex = sel[idx];
    shx[lane] = ex;
    __syncthreads();
    int pre = 0;
#pragma unroll
    for (int j = 0; j < 64; ++j) pre += (int)((j < lane) && (shx[j] == ex));
    const int pos = cbase[c * 64 + ex] + pre;
    out_sc[pos]  = ts[idx];
    out_idx[pos] = (float)(idx >> 1);
}

extern "C" void kernel_launch(void* const* d_in, const int* in_sizes, int n_in,
                              void* d_out, int out_size, void* d_ws, size_t ws_size,
                              hipStream_t stream)
{
    const float* x = (const float*)d_in[0];
    const float* W = (const float*)d_in[1];
    const float* b = (const float*)d_in[2];
    const int* bs_p = (const int*)d_in[3];
    const int* sl_p = (const int*)d_in[4];

    const int E   = in_sizes[2];           // 64
    const int dim = in_sizes[1] / E;       // 2048
    const int N   = in_sizes[0] / dim;     // 16384
    const int total = N * 2;               // slots
    const int nchunks = total / 64;        // 512

    char* ws = (char*)d_ws;
    size_t off = 0;
    int*    hist     = (int*)(ws + off); off += 256;
    double* bsum     = (double*)(ws + off); off += 512;
    int*    nflags   = (int*)(ws + off); off += 256;
    int*    estart   = (int*)(ws + off); off += 256;
    float*  ts       = (float*)(ws + off); off += (size_t)total * 4;
    int*    sel      = (int*)(ws + off); off += (size_t)total * 4;
    int*    flaglist = (int*)(ws + off); off += (size_t)N * 4;
    float*  rzrow    = (float*)(ws + off); off += (size_t)N * 4;
    int*    cnt2     = (int*)(ws + off); off += (size_t)nchunks * 64 * 4;
    int*    cbase    = (int*)(ws + off); off += (size_t)nchunks * 64 * 4;
    unsigned short* wfg = (unsigned short*)(ws + off); off += (size_t)dim * 64 * 2 * 2;

    float* out_sc  = (float*)d_out;
    float* out_idx = out_sc + total;
    float* out_cnt = out_idx + total;
    float* out_rz  = out_cnt + E;

    hipMemsetAsync(ws, 0, 1280, stream);

    hipLaunchKernelGGL(wconv, dim3(dim * 64 / 256), dim3(256), 0, stream, W, wfg);
    hipLaunchKernelGGL(gemm_mfma, dim3(N / 64), dim3(512), 0, stream,
                       x, wfg, b, dim, N, ts, sel, rzrow, nflags, flaglist);
    hipLaunchKernelGGL(fixup, dim3(512), dim3(1024), 0, stream,
                       x, W, b, dim, nflags, flaglist, ts, sel);
    hipLaunchKernelGGL(hist_chunks, dim3(nchunks), dim3(64), 0, stream,
                       sel, nchunks, hist, cnt2);
    hipLaunchKernelGGL(rz_batch, dim3(64), dim3(256), 0, stream,
                       rzrow, bs_p, sl_p, bsum);
    hipLaunchKernelGGL(combine, dim3(1), dim3(64), 0, stream,
                       hist, estart, bsum, bs_p, out_cnt, out_rz);
    hipLaunchKernelGGL(chunk_scan, dim3(64), dim3(1024), 0, stream,
                       cnt2, estart, nchunks, cbase);
    hipLaunchKernelGGL(scatter, dim3(nchunks), dim3(64), 0, stream,
                       sel, ts, cbase, out_sc, out_idx);
}